// Round 13
// baseline (1011.219 us; speedup 1.0000x reference)
//
#include <hip/hip_runtime.h>

#define NN 100000
#define En 400000
#define Gn 2000
#define GRID 2048

typedef unsigned short u16;
typedef unsigned int u32;
typedef _Float16 f16;
typedef f16 f16x8 __attribute__((ext_vector_type(8)));
typedef float f32x4 __attribute__((ext_vector_type(4)));

// barrier that drains only LDS ops (global loads/atomics stay in flight)
__device__ __forceinline__ void lds_barrier() {
  asm volatile("s_waitcnt lgkmcnt(0)\ns_barrier" ::: "memory");
}

#define MFMA16(a, b, c) __builtin_amdgcn_mfma_f32_16x16x32_f16(a, b, c, 0, 0, 0)

// ---------------- weight prep: converts + pads (must precede k_prep2: Rb dep)

__global__ __launch_bounds__(256) void k_prepw(
    const float* __restrict__ Wn1, const float* __restrict__ Wn2,
    const float* __restrict__ Wc, const float* __restrict__ We2,
    const float* __restrict__ We1,
    f16* __restrict__ Wn1b, f16* __restrict__ Wn2b, f16* __restrict__ Wcb,
    f16* __restrict__ We2b, f16* __restrict__ Rb) {
  int i = blockIdx.x * 256 + threadIdx.x;
  if (i < 49152) {
    Wn1b[i] = (f16)Wn1[i];
  } else if (i < 98304) {
    int j = i - 49152;
    Wn2b[j] = (f16)Wn2[j];
  } else if (i < 147456) {
    int j = i - 98304;
    Wcb[j] = (f16)Wc[j];
  } else if (i < 319488) {
    int j = i - 147456;
    int l = j / 57344;
    int r = j - l * 57344;
    int row = r / 448;
    int k = r - row * 448;
    float v = (k < 428) ? We2[l * 54784 + row * 428 + k] : 0.f;
    We2b[j] = (f16)v;
  } else if (i < 749568) {
    int j = i - 319488;
    int l = j / 143360;
    int r = j - l * 143360;
    int row = r / 320;
    int k = r - row * 320;
    float v = 0.f;
    if (row < 428 && k < 300) v = We1[(size_t)l * 183184 + row * 428 + 128 + k];
    Rb[j] = (f16)v;
  }
}

// ---------------- prep2 (range-dispatched): T2 + Dtab + hinit ----------------
// [0,84): T2 (LDS-staged)   [84,6231): Dtab (3 x 2049)   [6231,18731): hinit
// Reads Rb (k_prepw output) — separate launch, ordering guaranteed.

#define P2_DTAB_BASE 84
#define P2_HINIT_BASE 6231
#define P2_TOTAL 18731

__global__ __launch_bounds__(256) void k_prep2(
    const float* __restrict__ We1, const float* __restrict__ edge_emb,
    const float* __restrict__ be1, const int* __restrict__ Z,
    const float* __restrict__ node_emb, const f16* __restrict__ Rb,
    f16* __restrict__ T2, f16* __restrict__ Dtab,
    float* __restrict__ h, float* __restrict__ out) {
  __shared__ __align__(16) float sS[64 * 128 + 64];
  const int tid = threadIdx.x;
  const int blk = blockIdx.x;

  if (blk < P2_DTAB_BASE) {
    // ---- T2[l][t][j] = edge_emb[t]·We1[l][j][:128] + be1[l][j] ----
    float* sWe = sS;
    float* sB = sS + 64 * 128;
    const int l = blk / 28;
    const int rb = blk - l * 28;
    const int jb = rb >> 2;
    const int tc = rb & 3;
    const int j0 = jb * 64;
    for (int idx = tid; idx < 64 * 32; idx += 256) {
      int row = idx >> 5, c = idx & 31;
      int gj = j0 + row;
      float4 v = make_float4(0.f, 0.f, 0.f, 0.f);
      if (gj < 428)
        v = *(const float4*)&We1[(size_t)l * 183184 + gj * 428 + c * 4];
      *(float4*)&sWe[row * 128 + c * 4] = v;
    }
    if (tid < 64) {
      int gj = j0 + tid;
      sB[tid] = (gj < 428) ? be1[l * 428 + gj] : 0.f;
    }
    lds_barrier();
    const int jl = tid & 63, tl = tid >> 6;
    const int gj = j0 + jl;
    for (int it = 0; it < 25; ++it) {
      int t = tc * 100 + it * 4 + tl;
      const float4* er = (const float4*)(edge_emb + t * 128);
      float s = 0.f;
#pragma unroll
      for (int d = 0; d < 32; ++d) {
        float4 a = er[d];
        float4 b4 = *(const float4*)&sWe[jl * 128 + d * 4];
        s += a.x * b4.x + a.y * b4.y + a.z * b4.z + a.w * b4.w;
      }
      s += sB[jl];
      T2[l * 179200 + t * 448 + gj] = (gj < 428) ? (f16)s : (f16)0.f;
    }
    return;
  }

  if (blk < P2_HINIT_BASE) {
    // ---- Dtab[l][g][j] = sum_k rbf_k(g*delta) * R[l][j][k] ----
    float* sE = sS;
    const int b = blk - P2_DTAB_BASE;
    const int l = b / (GRID + 1);
    const int g = b - l * (GRID + 1);
    float d = (float)g * (30.f / (float)GRID);
    int kc = (int)(d * (299.f / 30.f) + 0.5f);
    int kk0 = min(max(kc - 16, 0), 268);
    if (tid < 32) {
      float x = d - (float)(kk0 + tid) * (30.f / 299.f);
      sE[tid] = __expf(-x * x * (299.f / 30.f));
    }
    __syncthreads();
    for (int j = tid; j < 448; j += 256) {
      const f16* rr = &Rb[((size_t)l * 448 + j) * 320 + kk0];
      float s = 0.f;
#pragma unroll
      for (int k = 0; k < 32; ++k) s += sE[k] * (float)rr[k];
      Dtab[((size_t)(l * (GRID + 1) + g)) * 448 + j] = (f16)s;
    }
    return;
  }

  // ---- hinit + out zero ----
  {
    int idx = (blk - P2_HINIT_BASE) * 256 + tid;
    if (idx < Gn) out[idx] = 0.f;
    int n = idx >> 5;
    int c = idx & 31;
    ((float4*)h)[idx] = ((const float4*)node_emb)[Z[n] * 32 + c];
  }
}

// ---------------- counting sort of edges by dst ----------------

__global__ __launch_bounds__(256) void k_zero32(u32* __restrict__ p, int n) {
  int i = blockIdx.x * 256 + threadIdx.x;
  if (i < n) p[i] = 0u;
}

__global__ __launch_bounds__(256) void k_hist(const int* __restrict__ dstv,
                                              u32* __restrict__ hist) {
  int e = blockIdx.x * 256 + threadIdx.x;
  if (e < En) atomicAdd(&hist[dstv[e]], 1u);
}

__global__ __launch_bounds__(1024) void k_scan1(const u32* __restrict__ hist,
                                                u32* __restrict__ excl,
                                                u32* __restrict__ part) {
  __shared__ u32 s[1024];
  const int t = threadIdx.x, b = blockIdx.x, i = b * 1024 + t;
  u32 v = (i < NN) ? hist[i] : 0u;
  s[t] = v;
  __syncthreads();
  u32 acc = v;
  for (int off = 1; off < 1024; off <<= 1) {
    u32 add = (t >= off) ? s[t - off] : 0u;
    __syncthreads();
    acc += add;
    s[t] = acc;
    __syncthreads();
  }
  if (i < NN) excl[i] = acc - v;
  if (t == 1023) part[b] = acc;
}

__global__ __launch_bounds__(128) void k_scan2(u32* __restrict__ part, int n) {
  __shared__ u32 s[128];
  const int t = threadIdx.x;
  u32 v = (t < n) ? part[t] : 0u;
  s[t] = v;
  __syncthreads();
  u32 acc = v;
  for (int off = 1; off < 128; off <<= 1) {
    u32 add = (t >= off) ? s[t - off] : 0u;
    __syncthreads();
    acc += add;
    s[t] = acc;
    __syncthreads();
  }
  if (t < n) part[t] = acc - v;
}

// scatter with inline scan3: pos = excl[d] + part[d>>10] + cursor[d]++
__global__ __launch_bounds__(256) void k_scatter(const int* __restrict__ etype,
                                                 const float* __restrict__ dist,
                                                 const int* __restrict__ srcv,
                                                 const int* __restrict__ dstv,
                                                 const u32* __restrict__ excl,
                                                 const u32* __restrict__ part,
                                                 u32* __restrict__ cursor,
                                                 int4* __restrict__ epack,
                                                 int* __restrict__ edst) {
  int e = blockIdx.x * 256 + threadIdx.x;
  if (e >= En) return;
  int d = dstv[e];
  int pos = (int)(excl[d] + part[d >> 10] + atomicAdd(&cursor[d], 1u));
  float fi = dist[e] * ((float)GRID / 30.f);
  int ix = (int)fi;
  epack[pos] = make_int4(srcv[e], etype[e] * 448, ix * 448,
                         __float_as_int(fi - (float)ix));
  edst[pos] = d;
}

// ---------------- node MLP: n2 = relu(h@W1^T+b1)@W2^T+b2  (f16 out) ----------------

__global__ __launch_bounds__(256) void k_node(const float* __restrict__ h,
                                              const f16* __restrict__ W1,
                                              const float* __restrict__ b1,
                                              const f16* __restrict__ W2,
                                              const float* __restrict__ b2,
                                              f16* __restrict__ n2) {
  __shared__ __align__(16) f16 sH[64 * 136];
  __shared__ __align__(16) f16 sT[64 * 136];
  const int tid = threadIdx.x;
  const int nbase = blockIdx.x * 64;
  for (int i = tid; i < 64 * 128; i += 256) {
    int e = i >> 7, d = i & 127;
    int node = nbase + e;
    float v = (node < NN) ? h[(size_t)node * 128 + d] : 0.f;
    sH[e * 136 + d] = (f16)v;
  }
  lds_barrier();
  const int lane = tid & 63, wave = tid >> 6;
  const int q = lane >> 4, ln = lane & 15;
  const int nb = wave * 32;

  f32x4 acc[4][2];
#pragma unroll
  for (int m = 0; m < 4; ++m)
#pragma unroll
    for (int n = 0; n < 2; ++n) acc[m][n] = 0.f;
#pragma unroll
  for (int k0 = 0; k0 < 128; k0 += 32) {
    f16x8 a[4];
#pragma unroll
    for (int m = 0; m < 4; ++m)
      a[m] = *(const f16x8*)&sH[(m * 16 + ln) * 136 + k0 + q * 8];
#pragma unroll
    for (int n = 0; n < 2; ++n) {
      f16x8 b = *(const f16x8*)&W1[(nb + n * 16 + ln) * 128 + k0 + q * 8];
#pragma unroll
      for (int m = 0; m < 4; ++m) acc[m][n] = MFMA16(a[m], b, acc[m][n]);
    }
  }
#pragma unroll
  for (int n = 0; n < 2; ++n) {
    int col = nb + n * 16 + ln;
    float bb = b1[col];
#pragma unroll
    for (int m = 0; m < 4; ++m)
#pragma unroll
      for (int r = 0; r < 4; ++r) {
        int row = m * 16 + q * 4 + r;
        sT[row * 136 + col] = (f16)fmaxf(acc[m][n][r] + bb, 0.f);
      }
  }
  lds_barrier();

  f32x4 acc2[4][2];
#pragma unroll
  for (int m = 0; m < 4; ++m)
#pragma unroll
    for (int n = 0; n < 2; ++n) acc2[m][n] = 0.f;
#pragma unroll
  for (int k0 = 0; k0 < 128; k0 += 32) {
    f16x8 a[4];
#pragma unroll
    for (int m = 0; m < 4; ++m)
      a[m] = *(const f16x8*)&sT[(m * 16 + ln) * 136 + k0 + q * 8];
#pragma unroll
    for (int n = 0; n < 2; ++n) {
      f16x8 b = *(const f16x8*)&W2[(nb + n * 16 + ln) * 128 + k0 + q * 8];
#pragma unroll
      for (int m = 0; m < 4; ++m) acc2[m][n] = MFMA16(a[m], b, acc2[m][n]);
    }
  }
#pragma unroll
  for (int n = 0; n < 2; ++n) {
    int col = nb + n * 16 + ln;
    float bb = b2[col];
#pragma unroll
    for (int m = 0; m < 4; ++m)
#pragma unroll
      for (int r = 0; r < 4; ++r) {
        int row = m * 16 + q * 4 + r;
        int node = nbase + row;
        if (node < NN) n2[(size_t)node * 128 + col] = (f16)(acc2[m][n][r] + bb);
      }
  }
}

// ---------------- fused edge kernel (one layer) ----------------
// 96-edge tile (m=6): 1.5x work per barrier at 3 blocks/CU (LDS 54.1 KB x3 =
// 162.4 KB < 160 KiB). Theory: barriers wait on gather *latency* which is
// ~constant per phase, so amortizing it over more edges wins more than the
// 16->12 wave drop costs. Known-bad: cross-phase reg state (r8), 8 blocks/CU
// (r9), paired Dtab (r11). Tail block: clamped meta + atomic guard.

__global__ __launch_bounds__(256, 3) void k_edge(
    const int4* __restrict__ epack, const int* __restrict__ edst,
    const f16* __restrict__ T2, const f16* __restrict__ Dtab,
    const f16* __restrict__ We2b, const float* __restrict__ be2,
    const f16* __restrict__ Wcb, const float* __restrict__ bc,
    const f16* __restrict__ n2, float* __restrict__ h) {
  __shared__ __align__(16) f16 sC[2][96 * 136];  // U K-chunks; sC[0]->n2, sC[1]->P
  __shared__ int sSrc[96], sDst[96], sT2o[96], sIdx[96];
  __shared__ float sFrac[96];

  const int tid = threadIdx.x;
  const int e0 = blockIdx.x * 96;
  const int elim = min(96, En - e0);
  if (tid < 96) {
    int ee = min(e0 + tid, En - 1);
    int4 p = epack[ee];
    sSrc[tid] = p.x;
    sT2o[tid] = p.y;
    sIdx[tid] = p.z;
    sFrac[tid] = __int_as_float(p.w);
    sDst[tid] = edst[ee];
  }
  lds_barrier();

  const int lane = tid & 63, wave = tid >> 6;
  const int q = lane >> 4, ln = lane & 15;
  const int nb = wave * 32;

  f32x4 acc[6][2];
#pragma unroll
  for (int m = 0; m < 6; ++m)
#pragma unroll
    for (int n = 0; n < 2; ++n) acc[m][n] = 0.f;

  auto lerp_relu = [](f16x8 lo, f16x8 hi, f16x8 t2, f16 fr) -> f16x8 {
    f16x8 v = t2 + lo + (hi - lo) * fr;
    f16x8 z = {};
    return __builtin_elementwise_max(v, z);
  };
  // 128-col chunk: 96 edges x 16 col-groups = 1536 units, 6/thread
  auto pf128 = [&](int k0, f16x8* plo, f16x8* phi, f16x8* pt2, f16* pfr) {
    const int cg = tid & 15, eb = tid >> 4;
    const int col = k0 + cg * 8;
#pragma unroll
    for (int i = 0; i < 6; ++i) {
      int e = eb + i * 16;
      int off = sIdx[e] + col;
      plo[i] = *(const f16x8*)&Dtab[off];
      phi[i] = *(const f16x8*)&Dtab[off + 448];
      pt2[i] = *(const f16x8*)&T2[sT2o[e] + col];
      pfr[i] = (f16)sFrac[e];
    }
  };
  auto st128 = [&](f16* buf, const f16x8* plo, const f16x8* phi,
                   const f16x8* pt2, const f16* pfr) {
    const int cg = tid & 15, eb = tid >> 4;
#pragma unroll
    for (int i = 0; i < 6; ++i) {
      int e = eb + i * 16;
      *(f16x8*)&buf[e * 136 + cg * 8] = lerp_relu(plo[i], phi[i], pt2[i], pfr[i]);
    }
  };
  // 64-col tail: 96 edges x 8 col-groups = 768 units, 3/thread
  auto pf64 = [&](f16x8* plo, f16x8* phi, f16x8* pt2, f16* pfr) {
    const int cg = tid & 7, eb = tid >> 3;
    const int col = 384 + cg * 8;
#pragma unroll
    for (int i = 0; i < 3; ++i) {
      int e = eb + i * 32;
      int off = sIdx[e] + col;
      plo[i] = *(const f16x8*)&Dtab[off];
      phi[i] = *(const f16x8*)&Dtab[off + 448];
      pt2[i] = *(const f16x8*)&T2[sT2o[e] + col];
      pfr[i] = (f16)sFrac[e];
    }
  };
  auto st64 = [&](f16* buf, const f16x8* plo, const f16x8* phi,
                  const f16x8* pt2, const f16* pfr) {
    const int cg = tid & 7, eb = tid >> 3;
#pragma unroll
    for (int i = 0; i < 3; ++i) {
      int e = eb + i * 32;
      *(f16x8*)&buf[e * 136 + cg * 8] = lerp_relu(plo[i], phi[i], pt2[i], pfr[i]);
    }
  };
  auto mfma_chunk = [&](const f16* buf, int k0, int nk) {
    for (int kk = 0; kk < nk; ++kk) {
      f16x8 a[6];
#pragma unroll
      for (int m = 0; m < 6; ++m)
        a[m] = *(const f16x8*)&buf[(m * 16 + ln) * 136 + kk * 32 + q * 8];
#pragma unroll
      for (int n = 0; n < 2; ++n) {
        f16x8 b = *(const f16x8*)&We2b[(nb + n * 16 + ln) * 448 + k0 + kk * 32 + q * 8];
#pragma unroll
        for (int m = 0; m < 6; ++m) acc[m][n] = MFMA16(a[m], b, acc[m][n]);
      }
    }
  };

  // pipelined chunk schedule
  {
    f16x8 plo[6], phi[6], pt2[6]; f16 pfr[6];
    pf128(0, plo, phi, pt2, pfr);
    st128(sC[0], plo, phi, pt2, pfr);
  }
  lds_barrier();
  {
    f16x8 plo[6], phi[6], pt2[6]; f16 pfr[6];
    pf128(128, plo, phi, pt2, pfr);
    mfma_chunk(sC[0], 0, 4);
    st128(sC[1], plo, phi, pt2, pfr);
  }
  lds_barrier();
  {
    f16x8 plo[6], phi[6], pt2[6]; f16 pfr[6];
    pf128(256, plo, phi, pt2, pfr);
    mfma_chunk(sC[1], 128, 4);
    st128(sC[0], plo, phi, pt2, pfr);
  }
  lds_barrier();
  f16x8 nrows[6];  // n2 row staging: u = tid + 256*i -> e=u>>4, cg=u&15
  {
    f16x8 plo[3], phi[3], pt2[3]; f16 pfr[3];
    pf64(plo, phi, pt2, pfr);
#pragma unroll
    for (int i = 0; i < 6; ++i) {
      int u = tid + 256 * i;
      int e = u >> 4, cg = u & 15;
      nrows[i] = *(const f16x8*)&n2[(size_t)sSrc[e] * 128 + cg * 8];
    }
    mfma_chunk(sC[0], 256, 4);
    st64(sC[1], plo, phi, pt2, pfr);
  }
  lds_barrier();  // sC[0] now free for all waves

  f16* sN = sC[0];
#pragma unroll
  for (int i = 0; i < 6; ++i) {
    int u = tid + 256 * i;
    int e = u >> 4, cg = u & 15;
    *(f16x8*)&sN[e * 136 + cg * 8] = nrows[i];
  }
  mfma_chunk(sC[1], 384, 2);
  lds_barrier();  // all waves done with sC[1]; reuse as P

  // epilogue 2: P = (EE + be2) * n2[src] -> sP (= sC[1])
  f16* sP = sC[1];
  {
    float be2v[2] = {be2[nb + ln], be2[nb + 16 + ln]};
#pragma unroll
    for (int n = 0; n < 2; ++n) {
      int col = nb + n * 16 + ln;
#pragma unroll
      for (int m = 0; m < 6; ++m)
#pragma unroll
        for (int r = 0; r < 4; ++r) {
          int row = m * 16 + q * 4 + r;
          float ee = acc[m][n][r] + be2v[n];
          sP[row * 136 + col] = (f16)(ee * (float)sN[row * 136 + col]);
        }
    }
  }
  lds_barrier();

  // phase 3: m = tanh(P @ Wc^T + bc); h[dst] += m  (run-merged atomics)
  {
    f32x4 acc2[6][2];
#pragma unroll
    for (int m = 0; m < 6; ++m)
#pragma unroll
      for (int n = 0; n < 2; ++n) acc2[m][n] = 0.f;
#pragma unroll
    for (int k0 = 0; k0 < 128; k0 += 32) {
      f16x8 a[6];
#pragma unroll
      for (int m = 0; m < 6; ++m)
        a[m] = *(const f16x8*)&sP[(m * 16 + ln) * 136 + k0 + q * 8];
#pragma unroll
      for (int n = 0; n < 2; ++n) {
        f16x8 b = *(const f16x8*)&Wcb[(nb + n * 16 + ln) * 128 + k0 + q * 8];
#pragma unroll
        for (int m = 0; m < 6; ++m) acc2[m][n] = MFMA16(a[m], b, acc2[m][n]);
      }
    }
    float bcv[2] = {bc[nb + ln], bc[nb + 16 + ln]};
#pragma unroll
    for (int m = 0; m < 6; ++m) {
      const int r0 = m * 16 + q * 4;
      int d[4];
#pragma unroll
      for (int r = 0; r < 4; ++r) d[r] = sDst[r0 + r];
#pragma unroll
      for (int n = 0; n < 2; ++n) {
        int col = nb + n * 16 + ln;
        float tv[4];
#pragma unroll
        for (int r = 0; r < 4; ++r) {
          // Pade [3/2] tanh: inputs ~1e-3 scale, err << f16 ulp
          float x = acc2[m][n][r] + bcv[n];
          x = fminf(2.f, fmaxf(-2.f, x));
          float x2 = x * x;
          tv[r] = x * (15.f + x2) * __builtin_amdgcn_rcpf(15.f + 6.f * x2);
        }
        if (r0 + 3 < elim) {
          // fast path: all 4 rows valid — merge consecutive same-dst runs
          float s = tv[0];
          int cur = d[0];
#pragma unroll
          for (int r = 1; r < 4; ++r) {
            if (d[r] == cur) {
              s += tv[r];
            } else {
              unsafeAtomicAdd(&h[(size_t)cur * 128 + col], s);
              cur = d[r];
              s = tv[r];
            }
          }
          unsafeAtomicAdd(&h[(size_t)cur * 128 + col], s);
        } else {
          // tail block: per-row guard
#pragma unroll
          for (int r = 0; r < 4; ++r)
            if (r0 + r < elim)
              unsafeAtomicAdd(&h[(size_t)d[r] * 128 + col], tv[r]);
        }
      }
    }
  }
}

// ---------------- readout ----------------

__global__ __launch_bounds__(256) void k_read(const float* __restrict__ h,
                                              const float* __restrict__ Wr1,
                                              const float* __restrict__ br1,
                                              const float* __restrict__ Wr2,
                                              const float* __restrict__ br2,
                                              const int* __restrict__ gid,
                                              float* __restrict__ out) {
  __shared__ __align__(16) f16 sH[64 * 136];
  __shared__ __align__(16) f16 sW[128 * 136];
  __shared__ float sR4[4][64];
  const int tid = threadIdx.x;
  const int nbase = blockIdx.x * 64;
  for (int i = tid; i < 64 * 128; i += 256) {
    int e = i >> 7, d = i & 127;
    int node = nbase + e;
    float v = (node < NN) ? h[(size_t)node * 128 + d] : 0.f;
    sH[e * 136 + d] = (f16)v;
  }
  for (int i = tid; i < 128 * 128; i += 256) {
    int rr = i >> 7, d = i & 127;
    sW[rr * 136 + d] = (f16)Wr1[i];
  }
  lds_barrier();
  const int lane = tid & 63, wave = tid >> 6;
  const int q = lane >> 4, ln = lane & 15;
  const int nb = wave * 32;

  f32x4 acc[4][2];
#pragma unroll
  for (int m = 0; m < 4; ++m)
#pragma unroll
    for (int n = 0; n < 2; ++n) acc[m][n] = 0.f;
#pragma unroll
  for (int k0 = 0; k0 < 128; k0 += 32) {
    f16x8 a[4];
#pragma unroll
    for (int m = 0; m < 4; ++m)
      a[m] = *(const f16x8*)&sH[(m * 16 + ln) * 136 + k0 + q * 8];
#pragma unroll
    for (int n = 0; n < 2; ++n) {
      f16x8 b = *(const f16x8*)&sW[(nb + n * 16 + ln) * 136 + k0 + q * 8];
#pragma unroll
      for (int m = 0; m < 4; ++m) acc[m][n] = MFMA16(a[m], b, acc[m][n]);
    }
  }
#pragma unroll
  for (int m = 0; m < 4; ++m)
#pragma unroll
    for (int r = 0; r < 4; ++r) {
      float t = 0.f;
#pragma unroll
      for (int n = 0; n < 2; ++n) {
        int col = nb + n * 16 + ln;
        t += fmaxf(acc[m][n][r] + br1[col], 0.f) * Wr2[col];
      }
      t += __shfl_xor(t, 1);
      t += __shfl_xor(t, 2);
      t += __shfl_xor(t, 4);
      t += __shfl_xor(t, 8);
      if (ln == 0) sR4[wave][m * 16 + q * 4 + r] = t;
    }
  lds_barrier();
  if (tid < 64) {
    int node = nbase + tid;
    if (node < NN) {
      float s = sR4[0][tid] + sR4[1][tid] + sR4[2][tid] + sR4[3][tid] + br2[0];
      unsafeAtomicAdd(&out[gid[node]], s);
    }
  }
}

// ---------------- launch ----------------

extern "C" void kernel_launch(void* const* d_in, const int* in_sizes, int n_in,
                              void* d_out, int out_size, void* d_ws, size_t ws_size,
                              hipStream_t stream) {
  const int* Z = (const int*)d_in[0];
  const int* etype = (const int*)d_in[1];
  const float* dist = (const float*)d_in[2];
  const int* src = (const int*)d_in[3];
  const int* dst = (const int*)d_in[4];
  const int* gid = (const int*)d_in[5];
  const float* node_emb = (const float*)d_in[6];
  const float* edge_emb = (const float*)d_in[7];
  const float* Wn1 = (const float*)d_in[8];
  const float* bn1 = (const float*)d_in[9];
  const float* Wn2 = (const float*)d_in[10];
  const float* bn2 = (const float*)d_in[11];
  const float* We1 = (const float*)d_in[12];
  const float* be1 = (const float*)d_in[13];
  const float* We2 = (const float*)d_in[14];
  const float* be2 = (const float*)d_in[15];
  const float* Wc = (const float*)d_in[16];
  const float* bc = (const float*)d_in[17];
  const float* Wr1 = (const float*)d_in[18];
  const float* br1 = (const float*)d_in[19];
  const float* Wr2 = (const float*)d_in[20];
  const float* br2 = (const float*)d_in[21];
  float* out = (float*)d_out;

  char* ws = (char*)d_ws;
  float* h = (float*)(ws);                   // 51,200,000 B
  f16* n2 = (f16*)(ws + 51200000);           // 25,600,000 B
  f16* Rb = (f16*)(ws + 76800000);           //    860,160 B
  f16* We2b = (f16*)(ws + 77660160);         //    344,064 B
  f16* Wcb = (f16*)(ws + 78004224);          //     98,304 B
  f16* Wn1b = (f16*)(ws + 78102528);         //     98,304 B
  f16* Wn2b = (f16*)(ws + 78200832);         //     98,304 B
  f16* T2 = (f16*)(ws + 78299136);           //  1,075,200 B
  f16* Dtab = (f16*)(ws + 79374336);         //  5,507,712 B  -> 84,882,048
  int4* epack = (int4*)(ws + 84882048);      //  6,400,000 B  -> 91,282,048
  int* edst = (int*)(ws + 91282048);         //  1,600,000 B  -> 92,882,048
  u32* hist = (u32*)(ws + 92882048);         //    400,000 B  -> 93,282,048
  u32* cursor = (u32*)(ws + 93282048);       //    400,000 B  (contiguous w/ hist)
  u32* excl = (u32*)(ws + 93682048);         //    400,000 B
  u32* part = (u32*)(ws + 94082048);         //        512 B  -> 94,082,560

  // edge sort by dst (once, reused by all 3 layers)
  k_zero32<<<782, 256, 0, stream>>>(hist, 2 * NN);  // hist + cursor
  k_hist<<<1563, 256, 0, stream>>>(dst, hist);
  k_scan1<<<98, 1024, 0, stream>>>(hist, excl, part);
  k_scan2<<<1, 128, 0, stream>>>(part, 98);
  k_scatter<<<1563, 256, 0, stream>>>(etype, dist, src, dst, excl, part, cursor,
                                      epack, edst);

  k_prepw<<<2928, 256, 0, stream>>>(Wn1, Wn2, Wc, We2, We1,
                                    Wn1b, Wn2b, Wcb, We2b, Rb);
  k_prep2<<<P2_TOTAL, 256, 0, stream>>>(We1, edge_emb, be1, Z, node_emb, Rb,
                                        T2, Dtab, h, out);

  for (int l = 0; l < 3; ++l) {
    k_node<<<1563, 256, 0, stream>>>(h, Wn1b + l * 16384, bn1 + l * 128,
                                     Wn2b + l * 16384, bn2 + l * 128, n2);
    k_edge<<<4167, 256, 0, stream>>>(epack, edst,
                                     T2 + l * 179200, Dtab + (size_t)l * (GRID + 1) * 448,
                                     We2b + l * 57344, be2 + l * 128,
                                     Wcb + l * 16384, bc + l * 128, n2, h);
  }
  k_read<<<1563, 256, 0, stream>>>(h, Wr1, br1, Wr2, br2, gid, out);
}

// Round 14
// 966.177 us; speedup vs baseline: 1.0466x; 1.0466x over previous
//
#include <hip/hip_runtime.h>

#define NN 100000
#define En 400000
#define Gn 2000
#define GRID 2048

typedef unsigned short u16;
typedef unsigned int u32;
typedef _Float16 f16;
typedef f16 f16x8 __attribute__((ext_vector_type(8)));
typedef float f32x4 __attribute__((ext_vector_type(4)));

// barrier that drains only LDS ops (global loads/atomics stay in flight)
__device__ __forceinline__ void lds_barrier() {
  asm volatile("s_waitcnt lgkmcnt(0)\ns_barrier" ::: "memory");
}

#define MFMA16(a, b, c) __builtin_amdgcn_mfma_f32_16x16x32_f16(a, b, c, 0, 0, 0)

// ---------------- fused weight prep: converts + pads ----------------

__global__ __launch_bounds__(256) void k_prepw(
    const float* __restrict__ Wn1, const float* __restrict__ Wn2,
    const float* __restrict__ Wc, const float* __restrict__ We2,
    const float* __restrict__ We1,
    f16* __restrict__ Wn1b, f16* __restrict__ Wn2b, f16* __restrict__ Wcb,
    f16* __restrict__ We2b, f16* __restrict__ Rb) {
  int i = blockIdx.x * 256 + threadIdx.x;
  if (i < 49152) {
    Wn1b[i] = (f16)Wn1[i];
  } else if (i < 98304) {
    int j = i - 49152;
    Wn2b[j] = (f16)Wn2[j];
  } else if (i < 147456) {
    int j = i - 98304;
    Wcb[j] = (f16)Wc[j];
  } else if (i < 319488) {
    int j = i - 147456;
    int l = j / 57344;
    int r = j - l * 57344;
    int row = r / 448;
    int k = r - row * 448;
    float v = (k < 428) ? We2[l * 54784 + row * 428 + k] : 0.f;
    We2b[j] = (f16)v;
  } else if (i < 749568) {
    int j = i - 319488;
    int l = j / 143360;
    int r = j - l * 143360;
    int row = r / 320;
    int k = r - row * 320;
    float v = 0.f;
    if (row < 428 && k < 300) v = We1[(size_t)l * 183184 + row * 428 + 128 + k];
    Rb[j] = (f16)v;
  }
}

// ---------------- T2 (tiled, LDS-staged) ----------------
// T2[l][t][j] = edge_emb[t]·We1[l][j][:128] + be1[l][j]   f16 [3][400][448]

__global__ __launch_bounds__(256) void k_t2(const float* __restrict__ edge_emb,
                                            const float* __restrict__ We1,
                                            const float* __restrict__ be1,
                                            f16* __restrict__ T2) {
  __shared__ __align__(16) float sWe[64][32 * 4];
  __shared__ float sB[64];
  const int tid = threadIdx.x;
  const int l = blockIdx.x / 28;
  const int rb = blockIdx.x - l * 28;
  const int jb = rb >> 2;
  const int tc = rb & 3;
  const int j0 = jb * 64;
  for (int idx = tid; idx < 64 * 32; idx += 256) {
    int row = idx >> 5, c = idx & 31;
    int gj = j0 + row;
    float4 v = make_float4(0.f, 0.f, 0.f, 0.f);
    if (gj < 428)
      v = *(const float4*)&We1[(size_t)l * 183184 + gj * 428 + c * 4];
    *(float4*)&sWe[row][c * 4] = v;
  }
  if (tid < 64) {
    int gj = j0 + tid;
    sB[tid] = (gj < 428) ? be1[l * 428 + gj] : 0.f;
  }
  lds_barrier();
  const int jl = tid & 63, tl = tid >> 6;
  const int gj = j0 + jl;
  for (int it = 0; it < 25; ++it) {
    int t = tc * 100 + it * 4 + tl;
    const float4* er = (const float4*)(edge_emb + t * 128);
    float s = 0.f;
#pragma unroll
    for (int d = 0; d < 32; ++d) {
      float4 a = er[d];
      float4 b = *(const float4*)&sWe[jl][d * 4];
      s += a.x * b.x + a.y * b.y + a.z * b.z + a.w * b.w;
    }
    s += sB[jl];
    T2[l * 179200 + t * 448 + gj] = (gj < 428) ? (f16)s : (f16)0.f;
  }
}

// Dtab[l][g][j] = sum_k rbf_k(g*delta) * R[l][j][k]   f16 [3][GRID+1][448]
__global__ __launch_bounds__(256) void k_dtab(const f16* __restrict__ Rb,
                                              f16* __restrict__ Dtab) {
  const int tid = threadIdx.x;
  int l = blockIdx.x / (GRID + 1);
  int g = blockIdx.x - l * (GRID + 1);
  float d = (float)g * (30.f / (float)GRID);
  int kc = (int)(d * (299.f / 30.f) + 0.5f);
  int kk0 = min(max(kc - 16, 0), 268);
  __shared__ float sE[32];
  if (tid < 32) {
    float x = d - (float)(kk0 + tid) * (30.f / 299.f);
    sE[tid] = __expf(-x * x * (299.f / 30.f));
  }
  __syncthreads();
  for (int j = tid; j < 448; j += 256) {
    const f16* rr = &Rb[((size_t)l * 448 + j) * 320 + kk0];
    float s = 0.f;
#pragma unroll
    for (int k = 0; k < 32; ++k) s += sE[k] * (float)rr[k];
    Dtab[((size_t)(l * (GRID + 1) + g)) * 448 + j] = (f16)s;
  }
}

// h[n][:] = node_emb[Z[n]][:]   (+ fused out[] zeroing)
__global__ __launch_bounds__(256) void k_hinit(const int* __restrict__ Z,
                                               const float* __restrict__ node_emb,
                                               float* __restrict__ h,
                                               float* __restrict__ out) {
  int idx = blockIdx.x * 256 + threadIdx.x;
  if (idx < Gn) out[idx] = 0.f;
  int n = idx >> 5;
  int c = idx & 31;
  ((float4*)h)[idx] = ((const float4*)node_emb)[Z[n] * 32 + c];
}

// ---------------- counting sort of edges by dst ----------------

__global__ __launch_bounds__(256) void k_zero32(u32* __restrict__ p, int n) {
  int i = blockIdx.x * 256 + threadIdx.x;
  if (i < n) p[i] = 0u;
}

__global__ __launch_bounds__(256) void k_hist(const int* __restrict__ dstv,
                                              u32* __restrict__ hist) {
  int e = blockIdx.x * 256 + threadIdx.x;
  if (e < En) atomicAdd(&hist[dstv[e]], 1u);
}

__global__ __launch_bounds__(1024) void k_scan1(const u32* __restrict__ hist,
                                                u32* __restrict__ excl,
                                                u32* __restrict__ part) {
  __shared__ u32 s[1024];
  const int t = threadIdx.x, b = blockIdx.x, i = b * 1024 + t;
  u32 v = (i < NN) ? hist[i] : 0u;
  s[t] = v;
  __syncthreads();
  u32 acc = v;
  for (int off = 1; off < 1024; off <<= 1) {
    u32 add = (t >= off) ? s[t - off] : 0u;
    __syncthreads();
    acc += add;
    s[t] = acc;
    __syncthreads();
  }
  if (i < NN) excl[i] = acc - v;
  if (t == 1023) part[b] = acc;
}

__global__ __launch_bounds__(128) void k_scan2(u32* __restrict__ part, int n) {
  __shared__ u32 s[128];
  const int t = threadIdx.x;
  u32 v = (t < n) ? part[t] : 0u;
  s[t] = v;
  __syncthreads();
  u32 acc = v;
  for (int off = 1; off < 128; off <<= 1) {
    u32 add = (t >= off) ? s[t - off] : 0u;
    __syncthreads();
    acc += add;
    s[t] = acc;
    __syncthreads();
  }
  if (t < n) part[t] = acc - v;
}

__global__ __launch_bounds__(1024) void k_scan3(const u32* __restrict__ excl,
                                                const u32* __restrict__ part,
                                                u32* __restrict__ cursor) {
  int i = blockIdx.x * 1024 + threadIdx.x;
  if (i < NN) cursor[i] = excl[i] + part[blockIdx.x];
}

__global__ __launch_bounds__(256) void k_scatter(const int* __restrict__ etype,
                                                 const float* __restrict__ dist,
                                                 const int* __restrict__ srcv,
                                                 const int* __restrict__ dstv,
                                                 u32* __restrict__ cursor,
                                                 int4* __restrict__ epack,
                                                 int* __restrict__ edst) {
  int e = blockIdx.x * 256 + threadIdx.x;
  if (e >= En) return;
  int d = dstv[e];
  int pos = (int)atomicAdd(&cursor[d], 1u);
  float fi = dist[e] * ((float)GRID / 30.f);
  int ix = (int)fi;
  epack[pos] = make_int4(srcv[e], etype[e] * 448, ix * 448,
                         __float_as_int(fi - (float)ix));
  edst[pos] = d;
}

// ---------------- node MLP: n2 = relu(h@W1^T+b1)@W2^T+b2  (f16 out) ----------------

__global__ __launch_bounds__(256) void k_node(const float* __restrict__ h,
                                              const f16* __restrict__ W1,
                                              const float* __restrict__ b1,
                                              const f16* __restrict__ W2,
                                              const float* __restrict__ b2,
                                              f16* __restrict__ n2) {
  __shared__ __align__(16) f16 sH[64 * 136];
  __shared__ __align__(16) f16 sT[64 * 136];
  const int tid = threadIdx.x;
  const int nbase = blockIdx.x * 64;
  for (int i = tid; i < 64 * 128; i += 256) {
    int e = i >> 7, d = i & 127;
    int node = nbase + e;
    float v = (node < NN) ? h[(size_t)node * 128 + d] : 0.f;
    sH[e * 136 + d] = (f16)v;
  }
  lds_barrier();
  const int lane = tid & 63, wave = tid >> 6;
  const int q = lane >> 4, ln = lane & 15;
  const int nb = wave * 32;

  f32x4 acc[4][2];
#pragma unroll
  for (int m = 0; m < 4; ++m)
#pragma unroll
    for (int n = 0; n < 2; ++n) acc[m][n] = 0.f;
#pragma unroll
  for (int k0 = 0; k0 < 128; k0 += 32) {
    f16x8 a[4];
#pragma unroll
    for (int m = 0; m < 4; ++m)
      a[m] = *(const f16x8*)&sH[(m * 16 + ln) * 136 + k0 + q * 8];
#pragma unroll
    for (int n = 0; n < 2; ++n) {
      f16x8 b = *(const f16x8*)&W1[(nb + n * 16 + ln) * 128 + k0 + q * 8];
#pragma unroll
      for (int m = 0; m < 4; ++m) acc[m][n] = MFMA16(a[m], b, acc[m][n]);
    }
  }
#pragma unroll
  for (int n = 0; n < 2; ++n) {
    int col = nb + n * 16 + ln;
    float bb = b1[col];
#pragma unroll
    for (int m = 0; m < 4; ++m)
#pragma unroll
      for (int r = 0; r < 4; ++r) {
        int row = m * 16 + q * 4 + r;
        sT[row * 136 + col] = (f16)fmaxf(acc[m][n][r] + bb, 0.f);
      }
  }
  lds_barrier();

  f32x4 acc2[4][2];
#pragma unroll
  for (int m = 0; m < 4; ++m)
#pragma unroll
    for (int n = 0; n < 2; ++n) acc2[m][n] = 0.f;
#pragma unroll
  for (int k0 = 0; k0 < 128; k0 += 32) {
    f16x8 a[4];
#pragma unroll
    for (int m = 0; m < 4; ++m)
      a[m] = *(const f16x8*)&sT[(m * 16 + ln) * 136 + k0 + q * 8];
#pragma unroll
    for (int n = 0; n < 2; ++n) {
      f16x8 b = *(const f16x8*)&W2[(nb + n * 16 + ln) * 128 + k0 + q * 8];
#pragma unroll
      for (int m = 0; m < 4; ++m) acc2[m][n] = MFMA16(a[m], b, acc2[m][n]);
    }
  }
#pragma unroll
  for (int n = 0; n < 2; ++n) {
    int col = nb + n * 16 + ln;
    float bb = b2[col];
#pragma unroll
    for (int m = 0; m < 4; ++m)
#pragma unroll
      for (int r = 0; r < 4; ++r) {
        int row = m * 16 + q * 4 + r;
        int node = nbase + row;
        if (node < NN) n2[(size_t)node * 128 + col] = (f16)(acc2[m][n][r] + bb);
      }
  }
}

// ---------------- fused edge kernel (one layer) ----------------
// Local-optimum config (measured): 64-edge tile, chunked pipeline, dst-sorted
// edges, LDS n2 staging, run-merged fp32 atomics, sP aliases sC[1].
// LDS 36,352 B -> exactly 4 blocks/CU, VGPR 64, no spills.
// Probed-and-regressed neighbors: cross-phase reg state (r8: spills),
// 8 blocks/CU (r9: VGPR-32 spills), paired Dtab (r11: L2 capacity),
// 96-edge tile (r13: LDS granularity -> 2 blocks/CU), barrier-free (r4),
// explicit dbuf pipelining (r3-class: neutral).

__global__ __launch_bounds__(256, 4) void k_edge(
    const int4* __restrict__ epack, const int* __restrict__ edst,
    const f16* __restrict__ T2, const f16* __restrict__ Dtab,
    const f16* __restrict__ We2b, const float* __restrict__ be2,
    const f16* __restrict__ Wcb, const float* __restrict__ bc,
    const f16* __restrict__ n2, float* __restrict__ h) {
  __shared__ __align__(16) f16 sC[2][64 * 136];  // U K-chunks; sC[0]->n2, sC[1]->P
  __shared__ int sSrc[64], sDst[64], sT2o[64], sIdx[64];
  __shared__ float sFrac[64];

  const int tid = threadIdx.x;
  const int e0 = blockIdx.x * 64;
  if (tid < 64) {
    int4 p = epack[e0 + tid];
    sSrc[tid] = p.x;
    sT2o[tid] = p.y;
    sIdx[tid] = p.z;
    sFrac[tid] = __int_as_float(p.w);
    sDst[tid] = edst[e0 + tid];
  }
  lds_barrier();

  const int lane = tid & 63, wave = tid >> 6;
  const int q = lane >> 4, ln = lane & 15;
  const int nb = wave * 32;

  f32x4 acc[4][2];
#pragma unroll
  for (int m = 0; m < 4; ++m)
#pragma unroll
    for (int n = 0; n < 2; ++n) acc[m][n] = 0.f;

  auto lerp_relu = [](f16x8 lo, f16x8 hi, f16x8 t2, f16 fr) -> f16x8 {
    f16x8 v = t2 + lo + (hi - lo) * fr;
    f16x8 z = {};
    return __builtin_elementwise_max(v, z);
  };
  auto pf128 = [&](int k0, f16x8* plo, f16x8* phi, f16x8* pt2, f16* pfr) {
    const int cg = tid & 15, eb = tid >> 4;
    const int col = k0 + cg * 8;
#pragma unroll
    for (int i = 0; i < 4; ++i) {
      int e = eb + i * 16;
      int off = sIdx[e] + col;
      plo[i] = *(const f16x8*)&Dtab[off];
      phi[i] = *(const f16x8*)&Dtab[off + 448];
      pt2[i] = *(const f16x8*)&T2[sT2o[e] + col];
      pfr[i] = (f16)sFrac[e];
    }
  };
  auto st128 = [&](f16* buf, const f16x8* plo, const f16x8* phi,
                   const f16x8* pt2, const f16* pfr) {
    const int cg = tid & 15, eb = tid >> 4;
#pragma unroll
    for (int i = 0; i < 4; ++i) {
      int e = eb + i * 16;
      *(f16x8*)&buf[e * 136 + cg * 8] = lerp_relu(plo[i], phi[i], pt2[i], pfr[i]);
    }
  };
  auto pf64 = [&](f16x8* plo, f16x8* phi, f16x8* pt2, f16* pfr) {
    const int cg = tid & 7, eb = tid >> 3;
    const int col = 384 + cg * 8;
#pragma unroll
    for (int i = 0; i < 2; ++i) {
      int e = eb + i * 32;
      int off = sIdx[e] + col;
      plo[i] = *(const f16x8*)&Dtab[off];
      phi[i] = *(const f16x8*)&Dtab[off + 448];
      pt2[i] = *(const f16x8*)&T2[sT2o[e] + col];
      pfr[i] = (f16)sFrac[e];
    }
  };
  auto st64 = [&](f16* buf, const f16x8* plo, const f16x8* phi,
                  const f16x8* pt2, const f16* pfr) {
    const int cg = tid & 7, eb = tid >> 3;
#pragma unroll
    for (int i = 0; i < 2; ++i) {
      int e = eb + i * 32;
      *(f16x8*)&buf[e * 136 + cg * 8] = lerp_relu(plo[i], phi[i], pt2[i], pfr[i]);
    }
  };
  auto mfma_chunk = [&](const f16* buf, int k0, int nk) {
    for (int kk = 0; kk < nk; ++kk) {
      f16x8 a[4];
#pragma unroll
      for (int m = 0; m < 4; ++m)
        a[m] = *(const f16x8*)&buf[(m * 16 + ln) * 136 + kk * 32 + q * 8];
#pragma unroll
      for (int n = 0; n < 2; ++n) {
        f16x8 b = *(const f16x8*)&We2b[(nb + n * 16 + ln) * 448 + k0 + kk * 32 + q * 8];
#pragma unroll
        for (int m = 0; m < 4; ++m) acc[m][n] = MFMA16(a[m], b, acc[m][n]);
      }
    }
  };

  // pipelined chunk schedule
  {
    f16x8 plo[4], phi[4], pt2[4]; f16 pfr[4];
    pf128(0, plo, phi, pt2, pfr);
    st128(sC[0], plo, phi, pt2, pfr);
  }
  lds_barrier();
  {
    f16x8 plo[4], phi[4], pt2[4]; f16 pfr[4];
    pf128(128, plo, phi, pt2, pfr);
    mfma_chunk(sC[0], 0, 4);
    st128(sC[1], plo, phi, pt2, pfr);
  }
  lds_barrier();
  {
    f16x8 plo[4], phi[4], pt2[4]; f16 pfr[4];
    pf128(256, plo, phi, pt2, pfr);
    mfma_chunk(sC[1], 128, 4);
    st128(sC[0], plo, phi, pt2, pfr);
  }
  lds_barrier();
  f16x8 nrows[4];  // n2 row staging: u = tid + 256*i -> e=u>>4, cg=u&15
  {
    f16x8 plo[2], phi[2], pt2[2]; f16 pfr[2];
    pf64(plo, phi, pt2, pfr);
#pragma unroll
    for (int i = 0; i < 4; ++i) {
      int u = tid + 256 * i;
      int e = u >> 4, cg = u & 15;
      nrows[i] = *(const f16x8*)&n2[(size_t)sSrc[e] * 128 + cg * 8];
    }
    mfma_chunk(sC[0], 256, 4);
    st64(sC[1], plo, phi, pt2, pfr);
  }
  lds_barrier();  // sC[0] now free for all waves

  f16* sN = sC[0];
#pragma unroll
  for (int i = 0; i < 4; ++i) {
    int u = tid + 256 * i;
    int e = u >> 4, cg = u & 15;
    *(f16x8*)&sN[e * 136 + cg * 8] = nrows[i];
  }
  mfma_chunk(sC[1], 384, 2);
  lds_barrier();  // all waves done with sC[1]; reuse as P

  // epilogue 2: P = (EE + be2) * n2[src] -> sP (= sC[1])
  f16* sP = sC[1];
  {
    float be2v[2] = {be2[nb + ln], be2[nb + 16 + ln]};
#pragma unroll
    for (int n = 0; n < 2; ++n) {
      int col = nb + n * 16 + ln;
#pragma unroll
      for (int m = 0; m < 4; ++m)
#pragma unroll
        for (int r = 0; r < 4; ++r) {
          int row = m * 16 + q * 4 + r;
          float ee = acc[m][n][r] + be2v[n];
          sP[row * 136 + col] = (f16)(ee * (float)sN[row * 136 + col]);
        }
    }
  }
  lds_barrier();

  // phase 3: m = tanh(P @ Wc^T + bc); h[dst] += m  (run-merged atomics)
  {
    f32x4 acc2[4][2];
#pragma unroll
    for (int m = 0; m < 4; ++m)
#pragma unroll
      for (int n = 0; n < 2; ++n) acc2[m][n] = 0.f;
#pragma unroll
    for (int k0 = 0; k0 < 128; k0 += 32) {
      f16x8 a[4];
#pragma unroll
      for (int m = 0; m < 4; ++m)
        a[m] = *(const f16x8*)&sP[(m * 16 + ln) * 136 + k0 + q * 8];
#pragma unroll
      for (int n = 0; n < 2; ++n) {
        f16x8 b = *(const f16x8*)&Wcb[(nb + n * 16 + ln) * 128 + k0 + q * 8];
#pragma unroll
        for (int m = 0; m < 4; ++m) acc2[m][n] = MFMA16(a[m], b, acc2[m][n]);
      }
    }
    float bcv[2] = {bc[nb + ln], bc[nb + 16 + ln]};
#pragma unroll
    for (int m = 0; m < 4; ++m) {
      int d[4];
#pragma unroll
      for (int r = 0; r < 4; ++r) d[r] = sDst[m * 16 + q * 4 + r];
#pragma unroll
      for (int n = 0; n < 2; ++n) {
        int col = nb + n * 16 + ln;
        float tv[4];
#pragma unroll
        for (int r = 0; r < 4; ++r) {
          // Pade [3/2] tanh: inputs ~1e-3 scale, err << f16 ulp
          float x = acc2[m][n][r] + bcv[n];
          x = fminf(2.f, fmaxf(-2.f, x));
          float x2 = x * x;
          tv[r] = x * (15.f + x2) * __builtin_amdgcn_rcpf(15.f + 6.f * x2);
        }
        float s = tv[0];
        int cur = d[0];
#pragma unroll
        for (int r = 1; r < 4; ++r) {
          if (d[r] == cur) {
            s += tv[r];
          } else {
            unsafeAtomicAdd(&h[(size_t)cur * 128 + col], s);
            cur = d[r];
            s = tv[r];
          }
        }
        unsafeAtomicAdd(&h[(size_t)cur * 128 + col], s);
      }
    }
  }
}

// ---------------- readout ----------------

__global__ __launch_bounds__(256) void k_read(const float* __restrict__ h,
                                              const float* __restrict__ Wr1,
                                              const float* __restrict__ br1,
                                              const float* __restrict__ Wr2,
                                              const float* __restrict__ br2,
                                              const int* __restrict__ gid,
                                              float* __restrict__ out) {
  __shared__ __align__(16) f16 sH[64 * 136];
  __shared__ __align__(16) f16 sW[128 * 136];
  __shared__ float sR4[4][64];
  const int tid = threadIdx.x;
  const int nbase = blockIdx.x * 64;
  for (int i = tid; i < 64 * 128; i += 256) {
    int e = i >> 7, d = i & 127;
    int node = nbase + e;
    float v = (node < NN) ? h[(size_t)node * 128 + d] : 0.f;
    sH[e * 136 + d] = (f16)v;
  }
  for (int i = tid; i < 128 * 128; i += 256) {
    int rr = i >> 7, d = i & 127;
    sW[rr * 136 + d] = (f16)Wr1[i];
  }
  lds_barrier();
  const int lane = tid & 63, wave = tid >> 6;
  const int q = lane >> 4, ln = lane & 15;
  const int nb = wave * 32;

  f32x4 acc[4][2];
#pragma unroll
  for (int m = 0; m < 4; ++m)
#pragma unroll
    for (int n = 0; n < 2; ++n) acc[m][n] = 0.f;
#pragma unroll
  for (int k0 = 0; k0 < 128; k0 += 32) {
    f16x8 a[4];
#pragma unroll
    for (int m = 0; m < 4; ++m)
      a[m] = *(const f16x8*)&sH[(m * 16 + ln) * 136 + k0 + q * 8];
#pragma unroll
    for (int n = 0; n < 2; ++n) {
      f16x8 b = *(const f16x8*)&sW[(nb + n * 16 + ln) * 136 + k0 + q * 8];
#pragma unroll
      for (int m = 0; m < 4; ++m) acc[m][n] = MFMA16(a[m], b, acc[m][n]);
    }
  }
#pragma unroll
  for (int m = 0; m < 4; ++m)
#pragma unroll
    for (int r = 0; r < 4; ++r) {
      float t = 0.f;
#pragma unroll
      for (int n = 0; n < 2; ++n) {
        int col = nb + n * 16 + ln;
        t += fmaxf(acc[m][n][r] + br1[col], 0.f) * Wr2[col];
      }
      t += __shfl_xor(t, 1);
      t += __shfl_xor(t, 2);
      t += __shfl_xor(t, 4);
      t += __shfl_xor(t, 8);
      if (ln == 0) sR4[wave][m * 16 + q * 4 + r] = t;
    }
  lds_barrier();
  if (tid < 64) {
    int node = nbase + tid;
    if (node < NN) {
      float s = sR4[0][tid] + sR4[1][tid] + sR4[2][tid] + sR4[3][tid] + br2[0];
      unsafeAtomicAdd(&out[gid[node]], s);
    }
  }
}

// ---------------- launch ----------------

extern "C" void kernel_launch(void* const* d_in, const int* in_sizes, int n_in,
                              void* d_out, int out_size, void* d_ws, size_t ws_size,
                              hipStream_t stream) {
  const int* Z = (const int*)d_in[0];
  const int* etype = (const int*)d_in[1];
  const float* dist = (const float*)d_in[2];
  const int* src = (const int*)d_in[3];
  const int* dst = (const int*)d_in[4];
  const int* gid = (const int*)d_in[5];
  const float* node_emb = (const float*)d_in[6];
  const float* edge_emb = (const float*)d_in[7];
  const float* Wn1 = (const float*)d_in[8];
  const float* bn1 = (const float*)d_in[9];
  const float* Wn2 = (const float*)d_in[10];
  const float* bn2 = (const float*)d_in[11];
  const float* We1 = (const float*)d_in[12];
  const float* be1 = (const float*)d_in[13];
  const float* We2 = (const float*)d_in[14];
  const float* be2 = (const float*)d_in[15];
  const float* Wc = (const float*)d_in[16];
  const float* bc = (const float*)d_in[17];
  const float* Wr1 = (const float*)d_in[18];
  const float* br1 = (const float*)d_in[19];
  const float* Wr2 = (const float*)d_in[20];
  const float* br2 = (const float*)d_in[21];
  float* out = (float*)d_out;

  char* ws = (char*)d_ws;
  float* h = (float*)(ws);                   // 51,200,000 B
  f16* n2 = (f16*)(ws + 51200000);           // 25,600,000 B
  f16* Rb = (f16*)(ws + 76800000);           //    860,160 B
  f16* We2b = (f16*)(ws + 77660160);         //    344,064 B
  f16* Wcb = (f16*)(ws + 78004224);          //     98,304 B
  f16* Wn1b = (f16*)(ws + 78102528);         //     98,304 B
  f16* Wn2b = (f16*)(ws + 78200832);         //     98,304 B
  f16* T2 = (f16*)(ws + 78299136);           //  1,075,200 B
  f16* Dtab = (f16*)(ws + 79374336);         //  5,507,712 B  -> 84,882,048
  int4* epack = (int4*)(ws + 84882048);      //  6,400,000 B  -> 91,282,048
  int* edst = (int*)(ws + 91282048);         //  1,600,000 B  -> 92,882,048
  u32* hist = (u32*)(ws + 92882048);         //    400,000 B  -> 93,282,048
  u32* cursor = (u32*)(ws + 93282048);       //    400,000 B  -> 93,682,048
  u32* excl = (u32*)(ws + 93682048);         //    400,000 B  -> 94,082,048
  u32* part = (u32*)(ws + 94082048);         //        512 B  -> 94,082,560

  // edge sort by dst (once, reused by all 3 layers)
  k_zero32<<<391, 256, 0, stream>>>(hist, NN);
  k_hist<<<1563, 256, 0, stream>>>(dst, hist);
  k_scan1<<<98, 1024, 0, stream>>>(hist, excl, part);
  k_scan2<<<1, 128, 0, stream>>>(part, 98);
  k_scan3<<<98, 1024, 0, stream>>>(excl, part, cursor);
  k_scatter<<<1563, 256, 0, stream>>>(etype, dist, src, dst, cursor, epack, edst);

  k_prepw<<<2928, 256, 0, stream>>>(Wn1, Wn2, Wc, We2, We1,
                                    Wn1b, Wn2b, Wcb, We2b, Rb);
  k_t2<<<84, 256, 0, stream>>>(edge_emb, We1, be1, T2);
  k_dtab<<<3 * (GRID + 1), 256, 0, stream>>>(Rb, Dtab);
  k_hinit<<<12500, 256, 0, stream>>>(Z, node_emb, h, out);

  for (int l = 0; l < 3; ++l) {
    k_node<<<1563, 256, 0, stream>>>(h, Wn1b + l * 16384, bn1 + l * 128,
                                     Wn2b + l * 16384, bn2 + l * 128, n2);
    k_edge<<<6250, 256, 0, stream>>>(epack, edst,
                                     T2 + l * 179200, Dtab + (size_t)l * (GRID + 1) * 448,
                                     We2b + l * 57344, be2 + l * 128,
                                     Wcb + l * 16384, bc + l * 128, n2, h);
  }
  k_read<<<1563, 256, 0, stream>>>(h, Wr1, br1, Wr2, br2, gid, out);
}

// Round 15
// 948.767 us; speedup vs baseline: 1.0658x; 1.0184x over previous
//
#include <hip/hip_runtime.h>

#define NN 100000
#define En 400000
#define Gn 2000
#define GRID 2048

typedef unsigned short u16;
typedef unsigned int u32;
typedef _Float16 f16;
typedef f16 f16x8 __attribute__((ext_vector_type(8)));
typedef float f32x4 __attribute__((ext_vector_type(4)));

// barrier that drains only LDS ops (global loads/atomics stay in flight)
__device__ __forceinline__ void lds_barrier() {
  asm volatile("s_waitcnt lgkmcnt(0)\ns_barrier" ::: "memory");
}

#define MFMA16(a, b, c) __builtin_amdgcn_mfma_f32_16x16x32_f16(a, b, c, 0, 0, 0)

// ---------------- fused weight prep: converts + pads ----------------

__global__ __launch_bounds__(256) void k_prepw(
    const float* __restrict__ Wn1, const float* __restrict__ Wn2,
    const float* __restrict__ Wc, const float* __restrict__ We2,
    const float* __restrict__ We1,
    f16* __restrict__ Wn1b, f16* __restrict__ Wn2b, f16* __restrict__ Wcb,
    f16* __restrict__ We2b, f16* __restrict__ Rb) {
  int i = blockIdx.x * 256 + threadIdx.x;
  if (i < 49152) {
    Wn1b[i] = (f16)Wn1[i];
  } else if (i < 98304) {
    int j = i - 49152;
    Wn2b[j] = (f16)Wn2[j];
  } else if (i < 147456) {
    int j = i - 98304;
    Wcb[j] = (f16)Wc[j];
  } else if (i < 319488) {
    int j = i - 147456;
    int l = j / 57344;
    int r = j - l * 57344;
    int row = r / 448;
    int k = r - row * 448;
    float v = (k < 428) ? We2[l * 54784 + row * 428 + k] : 0.f;
    We2b[j] = (f16)v;
  } else if (i < 749568) {
    int j = i - 319488;
    int l = j / 143360;
    int r = j - l * 143360;
    int row = r / 320;
    int k = r - row * 320;
    float v = 0.f;
    if (row < 428 && k < 300) v = We1[(size_t)l * 183184 + row * 428 + 128 + k];
    Rb[j] = (f16)v;
  }
}

// ---------------- T2 (tiled, LDS-staged) ----------------
// T2[l][t][j] = edge_emb[t]·We1[l][j][:128] + be1[l][j]   f16 [3][400][448]

__global__ __launch_bounds__(256) void k_t2(const float* __restrict__ edge_emb,
                                            const float* __restrict__ We1,
                                            const float* __restrict__ be1,
                                            f16* __restrict__ T2) {
  __shared__ __align__(16) float sWe[64][32 * 4];
  __shared__ float sB[64];
  const int tid = threadIdx.x;
  const int l = blockIdx.x / 28;
  const int rb = blockIdx.x - l * 28;
  const int jb = rb >> 2;
  const int tc = rb & 3;
  const int j0 = jb * 64;
  for (int idx = tid; idx < 64 * 32; idx += 256) {
    int row = idx >> 5, c = idx & 31;
    int gj = j0 + row;
    float4 v = make_float4(0.f, 0.f, 0.f, 0.f);
    if (gj < 428)
      v = *(const float4*)&We1[(size_t)l * 183184 + gj * 428 + c * 4];
    *(float4*)&sWe[row][c * 4] = v;
  }
  if (tid < 64) {
    int gj = j0 + tid;
    sB[tid] = (gj < 428) ? be1[l * 428 + gj] : 0.f;
  }
  lds_barrier();
  const int jl = tid & 63, tl = tid >> 6;
  const int gj = j0 + jl;
  for (int it = 0; it < 25; ++it) {
    int t = tc * 100 + it * 4 + tl;
    const float4* er = (const float4*)(edge_emb + t * 128);
    float s = 0.f;
#pragma unroll
    for (int d = 0; d < 32; ++d) {
      float4 a = er[d];
      float4 b = *(const float4*)&sWe[jl][d * 4];
      s += a.x * b.x + a.y * b.y + a.z * b.z + a.w * b.w;
    }
    s += sB[jl];
    T2[l * 179200 + t * 448 + gj] = (gj < 428) ? (f16)s : (f16)0.f;
  }
}

// Dtab[l][g][j] = sum_k rbf_k(g*delta) * R[l][j][k]   f16 [3][GRID+1][448]
__global__ __launch_bounds__(256) void k_dtab(const f16* __restrict__ Rb,
                                              f16* __restrict__ Dtab) {
  const int tid = threadIdx.x;
  int l = blockIdx.x / (GRID + 1);
  int g = blockIdx.x - l * (GRID + 1);
  float d = (float)g * (30.f / (float)GRID);
  int kc = (int)(d * (299.f / 30.f) + 0.5f);
  int kk0 = min(max(kc - 16, 0), 268);
  __shared__ float sE[32];
  if (tid < 32) {
    float x = d - (float)(kk0 + tid) * (30.f / 299.f);
    sE[tid] = __expf(-x * x * (299.f / 30.f));
  }
  __syncthreads();
  for (int j = tid; j < 448; j += 256) {
    const f16* rr = &Rb[((size_t)l * 448 + j) * 320 + kk0];
    float s = 0.f;
#pragma unroll
    for (int k = 0; k < 32; ++k) s += sE[k] * (float)rr[k];
    Dtab[((size_t)(l * (GRID + 1) + g)) * 448 + j] = (f16)s;
  }
}

// ---------------- counting sort of edges by dst ----------------

__global__ __launch_bounds__(256) void k_zero32(u32* __restrict__ p, int n) {
  int i = blockIdx.x * 256 + threadIdx.x;
  if (i < n) p[i] = 0u;
}

__global__ __launch_bounds__(256) void k_hist(const int* __restrict__ dstv,
                                              u32* __restrict__ hist) {
  int e = blockIdx.x * 256 + threadIdx.x;
  if (e < En) atomicAdd(&hist[dstv[e]], 1u);
}

__global__ __launch_bounds__(1024) void k_scan1(const u32* __restrict__ hist,
                                                u32* __restrict__ excl,
                                                u32* __restrict__ part) {
  __shared__ u32 s[1024];
  const int t = threadIdx.x, b = blockIdx.x, i = b * 1024 + t;
  u32 v = (i < NN) ? hist[i] : 0u;
  s[t] = v;
  __syncthreads();
  u32 acc = v;
  for (int off = 1; off < 1024; off <<= 1) {
    u32 add = (t >= off) ? s[t - off] : 0u;
    __syncthreads();
    acc += add;
    s[t] = acc;
    __syncthreads();
  }
  if (i < NN) excl[i] = acc - v;
  if (t == 1023) part[b] = acc;
}

__global__ __launch_bounds__(128) void k_scan2(u32* __restrict__ part, int n) {
  __shared__ u32 s[128];
  const int t = threadIdx.x;
  u32 v = (t < n) ? part[t] : 0u;
  s[t] = v;
  __syncthreads();
  u32 acc = v;
  for (int off = 1; off < 128; off <<= 1) {
    u32 add = (t >= off) ? s[t - off] : 0u;
    __syncthreads();
    acc += add;
    s[t] = acc;
    __syncthreads();
  }
  if (t < n) part[t] = acc - v;
}

__global__ __launch_bounds__(1024) void k_scan3(const u32* __restrict__ excl,
                                                const u32* __restrict__ part,
                                                u32* __restrict__ cursor) {
  int i = blockIdx.x * 1024 + threadIdx.x;
  if (i < NN) cursor[i] = excl[i] + part[blockIdx.x];
}

__global__ __launch_bounds__(256) void k_scatter(const int* __restrict__ etype,
                                                 const float* __restrict__ dist,
                                                 const int* __restrict__ srcv,
                                                 const int* __restrict__ dstv,
                                                 u32* __restrict__ cursor,
                                                 int4* __restrict__ epack,
                                                 int* __restrict__ edst) {
  int e = blockIdx.x * 256 + threadIdx.x;
  if (e >= En) return;
  int d = dstv[e];
  int pos = (int)atomicAdd(&cursor[d], 1u);
  float fi = dist[e] * ((float)GRID / 30.f);
  int ix = (int)fi;
  epack[pos] = make_int4(srcv[e], etype[e] * 448, ix * 448,
                         __float_as_int(fi - (float)ix));
  edst[pos] = d;
}

// ---------------- node MLP: n2 = relu(h@W1^T+b1)@W2^T+b2  (f16 out) ----------------

__global__ __launch_bounds__(256) void k_node(const float* __restrict__ h,
                                              const f16* __restrict__ W1,
                                              const float* __restrict__ b1,
                                              const f16* __restrict__ W2,
                                              const float* __restrict__ b2,
                                              f16* __restrict__ n2) {
  __shared__ __align__(16) f16 sH[64 * 136];
  __shared__ __align__(16) f16 sT[64 * 136];
  const int tid = threadIdx.x;
  const int nbase = blockIdx.x * 64;
  for (int i = tid; i < 64 * 128; i += 256) {
    int e = i >> 7, d = i & 127;
    int node = nbase + e;
    float v = (node < NN) ? h[(size_t)node * 128 + d] : 0.f;
    sH[e * 136 + d] = (f16)v;
  }
  lds_barrier();
  const int lane = tid & 63, wave = tid >> 6;
  const int q = lane >> 4, ln = lane & 15;
  const int nb = wave * 32;

  f32x4 acc[4][2];
#pragma unroll
  for (int m = 0; m < 4; ++m)
#pragma unroll
    for (int n = 0; n < 2; ++n) acc[m][n] = 0.f;
#pragma unroll
  for (int k0 = 0; k0 < 128; k0 += 32) {
    f16x8 a[4];
#pragma unroll
    for (int m = 0; m < 4; ++m)
      a[m] = *(const f16x8*)&sH[(m * 16 + ln) * 136 + k0 + q * 8];
#pragma unroll
    for (int n = 0; n < 2; ++n) {
      f16x8 b = *(const f16x8*)&W1[(nb + n * 16 + ln) * 128 + k0 + q * 8];
#pragma unroll
      for (int m = 0; m < 4; ++m) acc[m][n] = MFMA16(a[m], b, acc[m][n]);
    }
  }
#pragma unroll
  for (int n = 0; n < 2; ++n) {
    int col = nb + n * 16 + ln;
    float bb = b1[col];
#pragma unroll
    for (int m = 0; m < 4; ++m)
#pragma unroll
      for (int r = 0; r < 4; ++r) {
        int row = m * 16 + q * 4 + r;
        sT[row * 136 + col] = (f16)fmaxf(acc[m][n][r] + bb, 0.f);
      }
  }
  lds_barrier();

  f32x4 acc2[4][2];
#pragma unroll
  for (int m = 0; m < 4; ++m)
#pragma unroll
    for (int n = 0; n < 2; ++n) acc2[m][n] = 0.f;
#pragma unroll
  for (int k0 = 0; k0 < 128; k0 += 32) {
    f16x8 a[4];
#pragma unroll
    for (int m = 0; m < 4; ++m)
      a[m] = *(const f16x8*)&sT[(m * 16 + ln) * 136 + k0 + q * 8];
#pragma unroll
    for (int n = 0; n < 2; ++n) {
      f16x8 b = *(const f16x8*)&W2[(nb + n * 16 + ln) * 128 + k0 + q * 8];
#pragma unroll
      for (int m = 0; m < 4; ++m) acc2[m][n] = MFMA16(a[m], b, acc2[m][n]);
    }
  }
#pragma unroll
  for (int n = 0; n < 2; ++n) {
    int col = nb + n * 16 + ln;
    float bb = b2[col];
#pragma unroll
    for (int m = 0; m < 4; ++m)
#pragma unroll
      for (int r = 0; r < 4; ++r) {
        int row = m * 16 + q * 4 + r;
        int node = nbase + row;
        if (node < NN) n2[(size_t)node * 128 + col] = (f16)(acc2[m][n][r] + bb);
      }
  }
}

// ---------------- layer-0 node MLP fused with h-init ----------------
// Gathers node_emb[Z[n]] directly (20x128 table, L1-resident), writes h f32
// once, and runs the same MLP from LDS. Replaces k_hinit + k_node(l=0):
// saves one 51.2 MB h read + one launch. Also zeroes out[] (first 8 blocks).

__global__ __launch_bounds__(256) void k_node0(const int* __restrict__ Z,
                                               const float* __restrict__ node_emb,
                                               const f16* __restrict__ W1,
                                               const float* __restrict__ b1,
                                               const f16* __restrict__ W2,
                                               const float* __restrict__ b2,
                                               f16* __restrict__ n2,
                                               float* __restrict__ h,
                                               float* __restrict__ out) {
  __shared__ __align__(16) f16 sH[64 * 136];
  __shared__ __align__(16) f16 sT[64 * 136];
  __shared__ int sZ[64];
  const int tid = threadIdx.x;
  const int nbase = blockIdx.x * 64;
  {
    int oi = blockIdx.x * 256 + tid;
    if (oi < Gn) out[oi] = 0.f;
  }
  if (tid < 64) sZ[tid] = Z[min(nbase + tid, NN - 1)];
  lds_barrier();
  for (int i = tid; i < 64 * 128; i += 256) {
    int e = i >> 7, d = i & 127;
    int node = nbase + e;
    float v = node_emb[sZ[e] * 128 + d];
    sH[e * 136 + d] = (f16)v;
    if (node < NN) h[(size_t)node * 128 + d] = v;
  }
  lds_barrier();
  const int lane = tid & 63, wave = tid >> 6;
  const int q = lane >> 4, ln = lane & 15;
  const int nb = wave * 32;

  f32x4 acc[4][2];
#pragma unroll
  for (int m = 0; m < 4; ++m)
#pragma unroll
    for (int n = 0; n < 2; ++n) acc[m][n] = 0.f;
#pragma unroll
  for (int k0 = 0; k0 < 128; k0 += 32) {
    f16x8 a[4];
#pragma unroll
    for (int m = 0; m < 4; ++m)
      a[m] = *(const f16x8*)&sH[(m * 16 + ln) * 136 + k0 + q * 8];
#pragma unroll
    for (int n = 0; n < 2; ++n) {
      f16x8 b = *(const f16x8*)&W1[(nb + n * 16 + ln) * 128 + k0 + q * 8];
#pragma unroll
      for (int m = 0; m < 4; ++m) acc[m][n] = MFMA16(a[m], b, acc[m][n]);
    }
  }
#pragma unroll
  for (int n = 0; n < 2; ++n) {
    int col = nb + n * 16 + ln;
    float bb = b1[col];
#pragma unroll
    for (int m = 0; m < 4; ++m)
#pragma unroll
      for (int r = 0; r < 4; ++r) {
        int row = m * 16 + q * 4 + r;
        sT[row * 136 + col] = (f16)fmaxf(acc[m][n][r] + bb, 0.f);
      }
  }
  lds_barrier();

  f32x4 acc2[4][2];
#pragma unroll
  for (int m = 0; m < 4; ++m)
#pragma unroll
    for (int n = 0; n < 2; ++n) acc2[m][n] = 0.f;
#pragma unroll
  for (int k0 = 0; k0 < 128; k0 += 32) {
    f16x8 a[4];
#pragma unroll
    for (int m = 0; m < 4; ++m)
      a[m] = *(const f16x8*)&sT[(m * 16 + ln) * 136 + k0 + q * 8];
#pragma unroll
    for (int n = 0; n < 2; ++n) {
      f16x8 b = *(const f16x8*)&W2[(nb + n * 16 + ln) * 128 + k0 + q * 8];
#pragma unroll
      for (int m = 0; m < 4; ++m) acc2[m][n] = MFMA16(a[m], b, acc2[m][n]);
    }
  }
#pragma unroll
  for (int n = 0; n < 2; ++n) {
    int col = nb + n * 16 + ln;
    float bb = b2[col];
#pragma unroll
    for (int m = 0; m < 4; ++m)
#pragma unroll
      for (int r = 0; r < 4; ++r) {
        int row = m * 16 + q * 4 + r;
        int node = nbase + row;
        if (node < NN) n2[(size_t)node * 128 + col] = (f16)(acc2[m][n][r] + bb);
      }
  }
}

// ---------------- fused edge kernel (one layer) ----------------
// Local-optimum config (measured): 64-edge tile, chunked pipeline, dst-sorted
// edges, LDS n2 staging, run-merged fp32 atomics, sP aliases sC[1].
// LDS 36,352 B -> exactly 4 blocks/CU, VGPR 64, no spills.
// Probed-and-regressed neighbors: cross-phase reg state (r8: spills),
// 8 blocks/CU (r9: VGPR-32 spills), paired Dtab (r11: L2 capacity),
// 96-edge tile (r13: LDS granularity -> 2 blocks/CU), barrier-free (r4),
// explicit dbuf pipelining (r3-class: neutral).

__global__ __launch_bounds__(256, 4) void k_edge(
    const int4* __restrict__ epack, const int* __restrict__ edst,
    const f16* __restrict__ T2, const f16* __restrict__ Dtab,
    const f16* __restrict__ We2b, const float* __restrict__ be2,
    const f16* __restrict__ Wcb, const float* __restrict__ bc,
    const f16* __restrict__ n2, float* __restrict__ h) {
  __shared__ __align__(16) f16 sC[2][64 * 136];  // U K-chunks; sC[0]->n2, sC[1]->P
  __shared__ int sSrc[64], sDst[64], sT2o[64], sIdx[64];
  __shared__ float sFrac[64];

  const int tid = threadIdx.x;
  const int e0 = blockIdx.x * 64;
  if (tid < 64) {
    int4 p = epack[e0 + tid];
    sSrc[tid] = p.x;
    sT2o[tid] = p.y;
    sIdx[tid] = p.z;
    sFrac[tid] = __int_as_float(p.w);
    sDst[tid] = edst[e0 + tid];
  }
  lds_barrier();

  const int lane = tid & 63, wave = tid >> 6;
  const int q = lane >> 4, ln = lane & 15;
  const int nb = wave * 32;

  f32x4 acc[4][2];
#pragma unroll
  for (int m = 0; m < 4; ++m)
#pragma unroll
    for (int n = 0; n < 2; ++n) acc[m][n] = 0.f;

  auto lerp_relu = [](f16x8 lo, f16x8 hi, f16x8 t2, f16 fr) -> f16x8 {
    f16x8 v = t2 + lo + (hi - lo) * fr;
    f16x8 z = {};
    return __builtin_elementwise_max(v, z);
  };
  auto pf128 = [&](int k0, f16x8* plo, f16x8* phi, f16x8* pt2, f16* pfr) {
    const int cg = tid & 15, eb = tid >> 4;
    const int col = k0 + cg * 8;
#pragma unroll
    for (int i = 0; i < 4; ++i) {
      int e = eb + i * 16;
      int off = sIdx[e] + col;
      plo[i] = *(const f16x8*)&Dtab[off];
      phi[i] = *(const f16x8*)&Dtab[off + 448];
      pt2[i] = *(const f16x8*)&T2[sT2o[e] + col];
      pfr[i] = (f16)sFrac[e];
    }
  };
  auto st128 = [&](f16* buf, const f16x8* plo, const f16x8* phi,
                   const f16x8* pt2, const f16* pfr) {
    const int cg = tid & 15, eb = tid >> 4;
#pragma unroll
    for (int i = 0; i < 4; ++i) {
      int e = eb + i * 16;
      *(f16x8*)&buf[e * 136 + cg * 8] = lerp_relu(plo[i], phi[i], pt2[i], pfr[i]);
    }
  };
  auto pf64 = [&](f16x8* plo, f16x8* phi, f16x8* pt2, f16* pfr) {
    const int cg = tid & 7, eb = tid >> 3;
    const int col = 384 + cg * 8;
#pragma unroll
    for (int i = 0; i < 2; ++i) {
      int e = eb + i * 32;
      int off = sIdx[e] + col;
      plo[i] = *(const f16x8*)&Dtab[off];
      phi[i] = *(const f16x8*)&Dtab[off + 448];
      pt2[i] = *(const f16x8*)&T2[sT2o[e] + col];
      pfr[i] = (f16)sFrac[e];
    }
  };
  auto st64 = [&](f16* buf, const f16x8* plo, const f16x8* phi,
                  const f16x8* pt2, const f16* pfr) {
    const int cg = tid & 7, eb = tid >> 3;
#pragma unroll
    for (int i = 0; i < 2; ++i) {
      int e = eb + i * 32;
      *(f16x8*)&buf[e * 136 + cg * 8] = lerp_relu(plo[i], phi[i], pt2[i], pfr[i]);
    }
  };
  auto mfma_chunk = [&](const f16* buf, int k0, int nk) {
    for (int kk = 0; kk < nk; ++kk) {
      f16x8 a[4];
#pragma unroll
      for (int m = 0; m < 4; ++m)
        a[m] = *(const f16x8*)&buf[(m * 16 + ln) * 136 + kk * 32 + q * 8];
#pragma unroll
      for (int n = 0; n < 2; ++n) {
        f16x8 b = *(const f16x8*)&We2b[(nb + n * 16 + ln) * 448 + k0 + kk * 32 + q * 8];
#pragma unroll
        for (int m = 0; m < 4; ++m) acc[m][n] = MFMA16(a[m], b, acc[m][n]);
      }
    }
  };

  // pipelined chunk schedule
  {
    f16x8 plo[4], phi[4], pt2[4]; f16 pfr[4];
    pf128(0, plo, phi, pt2, pfr);
    st128(sC[0], plo, phi, pt2, pfr);
  }
  lds_barrier();
  {
    f16x8 plo[4], phi[4], pt2[4]; f16 pfr[4];
    pf128(128, plo, phi, pt2, pfr);
    mfma_chunk(sC[0], 0, 4);
    st128(sC[1], plo, phi, pt2, pfr);
  }
  lds_barrier();
  {
    f16x8 plo[4], phi[4], pt2[4]; f16 pfr[4];
    pf128(256, plo, phi, pt2, pfr);
    mfma_chunk(sC[1], 128, 4);
    st128(sC[0], plo, phi, pt2, pfr);
  }
  lds_barrier();
  f16x8 nrows[4];  // n2 row staging: u = tid + 256*i -> e=u>>4, cg=u&15
  {
    f16x8 plo[2], phi[2], pt2[2]; f16 pfr[2];
    pf64(plo, phi, pt2, pfr);
#pragma unroll
    for (int i = 0; i < 4; ++i) {
      int u = tid + 256 * i;
      int e = u >> 4, cg = u & 15;
      nrows[i] = *(const f16x8*)&n2[(size_t)sSrc[e] * 128 + cg * 8];
    }
    mfma_chunk(sC[0], 256, 4);
    st64(sC[1], plo, phi, pt2, pfr);
  }
  lds_barrier();  // sC[0] now free for all waves

  f16* sN = sC[0];
#pragma unroll
  for (int i = 0; i < 4; ++i) {
    int u = tid + 256 * i;
    int e = u >> 4, cg = u & 15;
    *(f16x8*)&sN[e * 136 + cg * 8] = nrows[i];
  }
  mfma_chunk(sC[1], 384, 2);
  lds_barrier();  // all waves done with sC[1]; reuse as P

  // epilogue 2: P = (EE + be2) * n2[src] -> sP (= sC[1])
  f16* sP = sC[1];
  {
    float be2v[2] = {be2[nb + ln], be2[nb + 16 + ln]};
#pragma unroll
    for (int n = 0; n < 2; ++n) {
      int col = nb + n * 16 + ln;
#pragma unroll
      for (int m = 0; m < 4; ++m)
#pragma unroll
        for (int r = 0; r < 4; ++r) {
          int row = m * 16 + q * 4 + r;
          float ee = acc[m][n][r] + be2v[n];
          sP[row * 136 + col] = (f16)(ee * (float)sN[row * 136 + col]);
        }
    }
  }
  lds_barrier();

  // phase 3: m = tanh(P @ Wc^T + bc); h[dst] += m  (run-merged atomics)
  {
    f32x4 acc2[4][2];
#pragma unroll
    for (int m = 0; m < 4; ++m)
#pragma unroll
      for (int n = 0; n < 2; ++n) acc2[m][n] = 0.f;
#pragma unroll
    for (int k0 = 0; k0 < 128; k0 += 32) {
      f16x8 a[4];
#pragma unroll
      for (int m = 0; m < 4; ++m)
        a[m] = *(const f16x8*)&sP[(m * 16 + ln) * 136 + k0 + q * 8];
#pragma unroll
      for (int n = 0; n < 2; ++n) {
        f16x8 b = *(const f16x8*)&Wcb[(nb + n * 16 + ln) * 128 + k0 + q * 8];
#pragma unroll
        for (int m = 0; m < 4; ++m) acc2[m][n] = MFMA16(a[m], b, acc2[m][n]);
      }
    }
    float bcv[2] = {bc[nb + ln], bc[nb + 16 + ln]};
#pragma unroll
    for (int m = 0; m < 4; ++m) {
      int d[4];
#pragma unroll
      for (int r = 0; r < 4; ++r) d[r] = sDst[m * 16 + q * 4 + r];
#pragma unroll
      for (int n = 0; n < 2; ++n) {
        int col = nb + n * 16 + ln;
        float tv[4];
#pragma unroll
        for (int r = 0; r < 4; ++r) {
          // Pade [3/2] tanh: inputs ~1e-3 scale, err << f16 ulp
          float x = acc2[m][n][r] + bcv[n];
          x = fminf(2.f, fmaxf(-2.f, x));
          float x2 = x * x;
          tv[r] = x * (15.f + x2) * __builtin_amdgcn_rcpf(15.f + 6.f * x2);
        }
        float s = tv[0];
        int cur = d[0];
#pragma unroll
        for (int r = 1; r < 4; ++r) {
          if (d[r] == cur) {
            s += tv[r];
          } else {
            unsafeAtomicAdd(&h[(size_t)cur * 128 + col], s);
            cur = d[r];
            s = tv[r];
          }
        }
        unsafeAtomicAdd(&h[(size_t)cur * 128 + col], s);
      }
    }
  }
}

// ---------------- readout ----------------

__global__ __launch_bounds__(256) void k_read(const float* __restrict__ h,
                                              const float* __restrict__ Wr1,
                                              const float* __restrict__ br1,
                                              const float* __restrict__ Wr2,
                                              const float* __restrict__ br2,
                                              const int* __restrict__ gid,
                                              float* __restrict__ out) {
  __shared__ __align__(16) f16 sH[64 * 136];
  __shared__ __align__(16) f16 sW[128 * 136];
  __shared__ float sR4[4][64];
  const int tid = threadIdx.x;
  const int nbase = blockIdx.x * 64;
  for (int i = tid; i < 64 * 128; i += 256) {
    int e = i >> 7, d = i & 127;
    int node = nbase + e;
    float v = (node < NN) ? h[(size_t)node * 128 + d] : 0.f;
    sH[e * 136 + d] = (f16)v;
  }
  for (int i = tid; i < 128 * 128; i += 256) {
    int rr = i >> 7, d = i & 127;
    sW[rr * 136 + d] = (f16)Wr1[i];
  }
  lds_barrier();
  const int lane = tid & 63, wave = tid >> 6;
  const int q = lane >> 4, ln = lane & 15;
  const int nb = wave * 32;

  f32x4 acc[4][2];
#pragma unroll
  for (int m = 0; m < 4; ++m)
#pragma unroll
    for (int n = 0; n < 2; ++n) acc[m][n] = 0.f;
#pragma unroll
  for (int k0 = 0; k0 < 128; k0 += 32) {
    f16x8 a[4];
#pragma unroll
    for (int m = 0; m < 4; ++m)
      a[m] = *(const f16x8*)&sH[(m * 16 + ln) * 136 + k0 + q * 8];
#pragma unroll
    for (int n = 0; n < 2; ++n) {
      f16x8 b = *(const f16x8*)&sW[(nb + n * 16 + ln) * 136 + k0 + q * 8];
#pragma unroll
      for (int m = 0; m < 4; ++m) acc[m][n] = MFMA16(a[m], b, acc[m][n]);
    }
  }
#pragma unroll
  for (int m = 0; m < 4; ++m)
#pragma unroll
    for (int r = 0; r < 4; ++r) {
      float t = 0.f;
#pragma unroll
      for (int n = 0; n < 2; ++n) {
        int col = nb + n * 16 + ln;
        t += fmaxf(acc[m][n][r] + br1[col], 0.f) * Wr2[col];
      }
      t += __shfl_xor(t, 1);
      t += __shfl_xor(t, 2);
      t += __shfl_xor(t, 4);
      t += __shfl_xor(t, 8);
      if (ln == 0) sR4[wave][m * 16 + q * 4 + r] = t;
    }
  lds_barrier();
  if (tid < 64) {
    int node = nbase + tid;
    if (node < NN) {
      float s = sR4[0][tid] + sR4[1][tid] + sR4[2][tid] + sR4[3][tid] + br2[0];
      unsafeAtomicAdd(&out[gid[node]], s);
    }
  }
}

// ---------------- launch ----------------

extern "C" void kernel_launch(void* const* d_in, const int* in_sizes, int n_in,
                              void* d_out, int out_size, void* d_ws, size_t ws_size,
                              hipStream_t stream) {
  const int* Z = (const int*)d_in[0];
  const int* etype = (const int*)d_in[1];
  const float* dist = (const float*)d_in[2];
  const int* src = (const int*)d_in[3];
  const int* dst = (const int*)d_in[4];
  const int* gid = (const int*)d_in[5];
  const float* node_emb = (const float*)d_in[6];
  const float* edge_emb = (const float*)d_in[7];
  const float* Wn1 = (const float*)d_in[8];
  const float* bn1 = (const float*)d_in[9];
  const float* Wn2 = (const float*)d_in[10];
  const float* bn2 = (const float*)d_in[11];
  const float* We1 = (const float*)d_in[12];
  const float* be1 = (const float*)d_in[13];
  const float* We2 = (const float*)d_in[14];
  const float* be2 = (const float*)d_in[15];
  const float* Wc = (const float*)d_in[16];
  const float* bc = (const float*)d_in[17];
  const float* Wr1 = (const float*)d_in[18];
  const float* br1 = (const float*)d_in[19];
  const float* Wr2 = (const float*)d_in[20];
  const float* br2 = (const float*)d_in[21];
  float* out = (float*)d_out;

  char* ws = (char*)d_ws;
  float* h = (float*)(ws);                   // 51,200,000 B
  f16* n2 = (f16*)(ws + 51200000);           // 25,600,000 B
  f16* Rb = (f16*)(ws + 76800000);           //    860,160 B
  f16* We2b = (f16*)(ws + 77660160);         //    344,064 B
  f16* Wcb = (f16*)(ws + 78004224);          //     98,304 B
  f16* Wn1b = (f16*)(ws + 78102528);         //     98,304 B
  f16* Wn2b = (f16*)(ws + 78200832);         //     98,304 B
  f16* T2 = (f16*)(ws + 78299136);           //  1,075,200 B
  f16* Dtab = (f16*)(ws + 79374336);         //  5,507,712 B  -> 84,882,048
  int4* epack = (int4*)(ws + 84882048);      //  6,400,000 B  -> 91,282,048
  int* edst = (int*)(ws + 91282048);         //  1,600,000 B  -> 92,882,048
  u32* hist = (u32*)(ws + 92882048);         //    400,000 B  -> 93,282,048
  u32* cursor = (u32*)(ws + 93282048);       //    400,000 B  -> 93,682,048
  u32* excl = (u32*)(ws + 93682048);         //    400,000 B  -> 94,082,048
  u32* part = (u32*)(ws + 94082048);         //        512 B  -> 94,082,560

  // edge sort by dst (once, reused by all 3 layers)
  k_zero32<<<391, 256, 0, stream>>>(hist, NN);
  k_hist<<<1563, 256, 0, stream>>>(dst, hist);
  k_scan1<<<98, 1024, 0, stream>>>(hist, excl, part);
  k_scan2<<<1, 128, 0, stream>>>(part, 98);
  k_scan3<<<98, 1024, 0, stream>>>(excl, part, cursor);
  k_scatter<<<1563, 256, 0, stream>>>(etype, dist, src, dst, cursor, epack, edst);

  k_prepw<<<2928, 256, 0, stream>>>(Wn1, Wn2, Wc, We2, We1,
                                    Wn1b, Wn2b, Wcb, We2b, Rb);
  k_t2<<<84, 256, 0, stream>>>(edge_emb, We1, be1, T2);
  k_dtab<<<3 * (GRID + 1), 256, 0, stream>>>(Rb, Dtab);

  for (int l = 0; l < 3; ++l) {
    if (l == 0) {
      k_node0<<<1563, 256, 0, stream>>>(Z, node_emb, Wn1b, bn1, Wn2b, bn2,
                                        n2, h, out);
    } else {
      k_node<<<1563, 256, 0, stream>>>(h, Wn1b + l * 16384, bn1 + l * 128,
                                       Wn2b + l * 16384, bn2 + l * 128, n2);
    }
    k_edge<<<6250, 256, 0, stream>>>(epack, edst,
                                     T2 + l * 179200, Dtab + (size_t)l * (GRID + 1) * 448,
                                     We2b + l * 57344, be2 + l * 128,
                                     Wcb + l * 16384, bc + l * 128, n2, h);
  }
  k_read<<<1563, 256, 0, stream>>>(h, Wr1, br1, Wr2, br2, gid, out);
}

// Round 16
// 946.235 us; speedup vs baseline: 1.0687x; 1.0027x over previous
//
#include <hip/hip_runtime.h>

#define NN 100000
#define En 400000
#define Gn 2000
#define GRID 2048

typedef unsigned short u16;
typedef unsigned int u32;
typedef _Float16 f16;
typedef f16 f16x8 __attribute__((ext_vector_type(8)));
typedef float f32x4 __attribute__((ext_vector_type(4)));

// barrier that drains only LDS ops (global loads/atomics stay in flight)
__device__ __forceinline__ void lds_barrier() {
  asm volatile("s_waitcnt lgkmcnt(0)\ns_barrier" ::: "memory");
}

#define MFMA16(a, b, c) __builtin_amdgcn_mfma_f32_16x16x32_f16(a, b, c, 0, 0, 0)

// ---------------- fused weight prep: converts + pads ----------------

__global__ __launch_bounds__(256) void k_prepw(
    const float* __restrict__ Wn1, const float* __restrict__ Wn2,
    const float* __restrict__ Wc, const float* __restrict__ We2,
    const float* __restrict__ We1,
    f16* __restrict__ Wn1b, f16* __restrict__ Wn2b, f16* __restrict__ Wcb,
    f16* __restrict__ We2b, f16* __restrict__ Rb) {
  int i = blockIdx.x * 256 + threadIdx.x;
  if (i < 49152) {
    Wn1b[i] = (f16)Wn1[i];
  } else if (i < 98304) {
    int j = i - 49152;
    Wn2b[j] = (f16)Wn2[j];
  } else if (i < 147456) {
    int j = i - 98304;
    Wcb[j] = (f16)Wc[j];
  } else if (i < 319488) {
    int j = i - 147456;
    int l = j / 57344;
    int r = j - l * 57344;
    int row = r / 448;
    int k = r - row * 448;
    float v = (k < 428) ? We2[l * 54784 + row * 428 + k] : 0.f;
    We2b[j] = (f16)v;
  } else if (i < 749568) {
    int j = i - 319488;
    int l = j / 143360;
    int r = j - l * 143360;
    int row = r / 320;
    int k = r - row * 320;
    float v = 0.f;
    if (row < 428 && k < 300) v = We1[(size_t)l * 183184 + row * 428 + 128 + k];
    Rb[j] = (f16)v;
  }
}

// ---------------- T2 (tiled, LDS-staged) ----------------
// T2[l][t][j] = edge_emb[t]·We1[l][j][:128] + be1[l][j]   f16 [3][400][448]

__global__ __launch_bounds__(256) void k_t2(const float* __restrict__ edge_emb,
                                            const float* __restrict__ We1,
                                            const float* __restrict__ be1,
                                            f16* __restrict__ T2) {
  __shared__ __align__(16) float sWe[64][32 * 4];
  __shared__ float sB[64];
  const int tid = threadIdx.x;
  const int l = blockIdx.x / 28;
  const int rb = blockIdx.x - l * 28;
  const int jb = rb >> 2;
  const int tc = rb & 3;
  const int j0 = jb * 64;
  for (int idx = tid; idx < 64 * 32; idx += 256) {
    int row = idx >> 5, c = idx & 31;
    int gj = j0 + row;
    float4 v = make_float4(0.f, 0.f, 0.f, 0.f);
    if (gj < 428)
      v = *(const float4*)&We1[(size_t)l * 183184 + gj * 428 + c * 4];
    *(float4*)&sWe[row][c * 4] = v;
  }
  if (tid < 64) {
    int gj = j0 + tid;
    sB[tid] = (gj < 428) ? be1[l * 428 + gj] : 0.f;
  }
  lds_barrier();
  const int jl = tid & 63, tl = tid >> 6;
  const int gj = j0 + jl;
  for (int it = 0; it < 25; ++it) {
    int t = tc * 100 + it * 4 + tl;
    const float4* er = (const float4*)(edge_emb + t * 128);
    float s = 0.f;
#pragma unroll
    for (int d = 0; d < 32; ++d) {
      float4 a = er[d];
      float4 b = *(const float4*)&sWe[jl][d * 4];
      s += a.x * b.x + a.y * b.y + a.z * b.z + a.w * b.w;
    }
    s += sB[jl];
    T2[l * 179200 + t * 448 + gj] = (gj < 428) ? (f16)s : (f16)0.f;
  }
}

// Dtab[l][g][j] = sum_k rbf_k(g*delta) * R[l][j][k]   f16 [3][GRID+1][448]
__global__ __launch_bounds__(256) void k_dtab(const f16* __restrict__ Rb,
                                              f16* __restrict__ Dtab) {
  const int tid = threadIdx.x;
  int l = blockIdx.x / (GRID + 1);
  int g = blockIdx.x - l * (GRID + 1);
  float d = (float)g * (30.f / (float)GRID);
  int kc = (int)(d * (299.f / 30.f) + 0.5f);
  int kk0 = min(max(kc - 16, 0), 268);
  __shared__ float sE[32];
  if (tid < 32) {
    float x = d - (float)(kk0 + tid) * (30.f / 299.f);
    sE[tid] = __expf(-x * x * (299.f / 30.f));
  }
  __syncthreads();
  for (int j = tid; j < 448; j += 256) {
    const f16* rr = &Rb[((size_t)l * 448 + j) * 320 + kk0];
    float s = 0.f;
#pragma unroll
    for (int k = 0; k < 32; ++k) s += sE[k] * (float)rr[k];
    Dtab[((size_t)(l * (GRID + 1) + g)) * 448 + j] = (f16)s;
  }
}

// ---------------- counting sort of edges by dst ----------------

__global__ __launch_bounds__(256) void k_zero32(u32* __restrict__ p, int n) {
  int i = blockIdx.x * 256 + threadIdx.x;
  if (i < n) p[i] = 0u;
}

__global__ __launch_bounds__(256) void k_hist(const int* __restrict__ dstv,
                                              u32* __restrict__ hist) {
  int e = blockIdx.x * 256 + threadIdx.x;
  if (e < En) atomicAdd(&hist[dstv[e]], 1u);
}

__global__ __launch_bounds__(1024) void k_scan1(const u32* __restrict__ hist,
                                                u32* __restrict__ excl,
                                                u32* __restrict__ part) {
  __shared__ u32 s[1024];
  const int t = threadIdx.x, b = blockIdx.x, i = b * 1024 + t;
  u32 v = (i < NN) ? hist[i] : 0u;
  s[t] = v;
  __syncthreads();
  u32 acc = v;
  for (int off = 1; off < 1024; off <<= 1) {
    u32 add = (t >= off) ? s[t - off] : 0u;
    __syncthreads();
    acc += add;
    s[t] = acc;
    __syncthreads();
  }
  if (i < NN) excl[i] = acc - v;
  if (t == 1023) part[b] = acc;
}

__global__ __launch_bounds__(128) void k_scan2(u32* __restrict__ part, int n) {
  __shared__ u32 s[128];
  const int t = threadIdx.x;
  u32 v = (t < n) ? part[t] : 0u;
  s[t] = v;
  __syncthreads();
  u32 acc = v;
  for (int off = 1; off < 128; off <<= 1) {
    u32 add = (t >= off) ? s[t - off] : 0u;
    __syncthreads();
    acc += add;
    s[t] = acc;
    __syncthreads();
  }
  if (t < n) part[t] = acc - v;
}

__global__ __launch_bounds__(1024) void k_scan3(const u32* __restrict__ excl,
                                                const u32* __restrict__ part,
                                                u32* __restrict__ cursor) {
  int i = blockIdx.x * 1024 + threadIdx.x;
  if (i < NN) cursor[i] = excl[i] + part[blockIdx.x];
}

__global__ __launch_bounds__(256) void k_scatter(const int* __restrict__ etype,
                                                 const float* __restrict__ dist,
                                                 const int* __restrict__ srcv,
                                                 const int* __restrict__ dstv,
                                                 u32* __restrict__ cursor,
                                                 int4* __restrict__ epack,
                                                 int* __restrict__ edst) {
  int e = blockIdx.x * 256 + threadIdx.x;
  if (e >= En) return;
  int d = dstv[e];
  int pos = (int)atomicAdd(&cursor[d], 1u);
  float fi = dist[e] * ((float)GRID / 30.f);
  int ix = (int)fi;
  epack[pos] = make_int4(srcv[e], etype[e] * 448, ix * 448,
                         __float_as_int(fi - (float)ix));
  edst[pos] = d;
}

// ---------------- node MLP: n2 = relu(h@W1^T+b1)@W2^T+b2  (f16 out) ----------------

__global__ __launch_bounds__(256) void k_node(const float* __restrict__ h,
                                              const f16* __restrict__ W1,
                                              const float* __restrict__ b1,
                                              const f16* __restrict__ W2,
                                              const float* __restrict__ b2,
                                              f16* __restrict__ n2) {
  __shared__ __align__(16) f16 sH[64 * 136];
  __shared__ __align__(16) f16 sT[64 * 136];
  const int tid = threadIdx.x;
  const int nbase = blockIdx.x * 64;
  for (int i = tid; i < 64 * 128; i += 256) {
    int e = i >> 7, d = i & 127;
    int node = nbase + e;
    float v = (node < NN) ? h[(size_t)node * 128 + d] : 0.f;
    sH[e * 136 + d] = (f16)v;
  }
  lds_barrier();
  const int lane = tid & 63, wave = tid >> 6;
  const int q = lane >> 4, ln = lane & 15;
  const int nb = wave * 32;

  f32x4 acc[4][2];
#pragma unroll
  for (int m = 0; m < 4; ++m)
#pragma unroll
    for (int n = 0; n < 2; ++n) acc[m][n] = 0.f;
#pragma unroll
  for (int k0 = 0; k0 < 128; k0 += 32) {
    f16x8 a[4];
#pragma unroll
    for (int m = 0; m < 4; ++m)
      a[m] = *(const f16x8*)&sH[(m * 16 + ln) * 136 + k0 + q * 8];
#pragma unroll
    for (int n = 0; n < 2; ++n) {
      f16x8 b = *(const f16x8*)&W1[(nb + n * 16 + ln) * 128 + k0 + q * 8];
#pragma unroll
      for (int m = 0; m < 4; ++m) acc[m][n] = MFMA16(a[m], b, acc[m][n]);
    }
  }
#pragma unroll
  for (int n = 0; n < 2; ++n) {
    int col = nb + n * 16 + ln;
    float bb = b1[col];
#pragma unroll
    for (int m = 0; m < 4; ++m)
#pragma unroll
      for (int r = 0; r < 4; ++r) {
        int row = m * 16 + q * 4 + r;
        sT[row * 136 + col] = (f16)fmaxf(acc[m][n][r] + bb, 0.f);
      }
  }
  lds_barrier();

  f32x4 acc2[4][2];
#pragma unroll
  for (int m = 0; m < 4; ++m)
#pragma unroll
    for (int n = 0; n < 2; ++n) acc2[m][n] = 0.f;
#pragma unroll
  for (int k0 = 0; k0 < 128; k0 += 32) {
    f16x8 a[4];
#pragma unroll
    for (int m = 0; m < 4; ++m)
      a[m] = *(const f16x8*)&sT[(m * 16 + ln) * 136 + k0 + q * 8];
#pragma unroll
    for (int n = 0; n < 2; ++n) {
      f16x8 b = *(const f16x8*)&W2[(nb + n * 16 + ln) * 128 + k0 + q * 8];
#pragma unroll
      for (int m = 0; m < 4; ++m) acc2[m][n] = MFMA16(a[m], b, acc2[m][n]);
    }
  }
#pragma unroll
  for (int n = 0; n < 2; ++n) {
    int col = nb + n * 16 + ln;
    float bb = b2[col];
#pragma unroll
    for (int m = 0; m < 4; ++m)
#pragma unroll
      for (int r = 0; r < 4; ++r) {
        int row = m * 16 + q * 4 + r;
        int node = nbase + row;
        if (node < NN) n2[(size_t)node * 128 + col] = (f16)(acc2[m][n][r] + bb);
      }
  }
}

// ---------------- layer-0 node MLP fused with h-init ----------------

__global__ __launch_bounds__(256) void k_node0(const int* __restrict__ Z,
                                               const float* __restrict__ node_emb,
                                               const f16* __restrict__ W1,
                                               const float* __restrict__ b1,
                                               const f16* __restrict__ W2,
                                               const float* __restrict__ b2,
                                               f16* __restrict__ n2,
                                               float* __restrict__ h,
                                               float* __restrict__ out) {
  __shared__ __align__(16) f16 sH[64 * 136];
  __shared__ __align__(16) f16 sT[64 * 136];
  __shared__ int sZ[64];
  const int tid = threadIdx.x;
  const int nbase = blockIdx.x * 64;
  {
    int oi = blockIdx.x * 256 + tid;
    if (oi < Gn) out[oi] = 0.f;
  }
  if (tid < 64) sZ[tid] = Z[min(nbase + tid, NN - 1)];
  lds_barrier();
  for (int i = tid; i < 64 * 128; i += 256) {
    int e = i >> 7, d = i & 127;
    int node = nbase + e;
    float v = node_emb[sZ[e] * 128 + d];
    sH[e * 136 + d] = (f16)v;
    if (node < NN) h[(size_t)node * 128 + d] = v;
  }
  lds_barrier();
  const int lane = tid & 63, wave = tid >> 6;
  const int q = lane >> 4, ln = lane & 15;
  const int nb = wave * 32;

  f32x4 acc[4][2];
#pragma unroll
  for (int m = 0; m < 4; ++m)
#pragma unroll
    for (int n = 0; n < 2; ++n) acc[m][n] = 0.f;
#pragma unroll
  for (int k0 = 0; k0 < 128; k0 += 32) {
    f16x8 a[4];
#pragma unroll
    for (int m = 0; m < 4; ++m)
      a[m] = *(const f16x8*)&sH[(m * 16 + ln) * 136 + k0 + q * 8];
#pragma unroll
    for (int n = 0; n < 2; ++n) {
      f16x8 b = *(const f16x8*)&W1[(nb + n * 16 + ln) * 128 + k0 + q * 8];
#pragma unroll
      for (int m = 0; m < 4; ++m) acc[m][n] = MFMA16(a[m], b, acc[m][n]);
    }
  }
#pragma unroll
  for (int n = 0; n < 2; ++n) {
    int col = nb + n * 16 + ln;
    float bb = b1[col];
#pragma unroll
    for (int m = 0; m < 4; ++m)
#pragma unroll
      for (int r = 0; r < 4; ++r) {
        int row = m * 16 + q * 4 + r;
        sT[row * 136 + col] = (f16)fmaxf(acc[m][n][r] + bb, 0.f);
      }
  }
  lds_barrier();

  f32x4 acc2[4][2];
#pragma unroll
  for (int m = 0; m < 4; ++m)
#pragma unroll
    for (int n = 0; n < 2; ++n) acc2[m][n] = 0.f;
#pragma unroll
  for (int k0 = 0; k0 < 128; k0 += 32) {
    f16x8 a[4];
#pragma unroll
    for (int m = 0; m < 4; ++m)
      a[m] = *(const f16x8*)&sT[(m * 16 + ln) * 136 + k0 + q * 8];
#pragma unroll
    for (int n = 0; n < 2; ++n) {
      f16x8 b = *(const f16x8*)&W2[(nb + n * 16 + ln) * 128 + k0 + q * 8];
#pragma unroll
      for (int m = 0; m < 4; ++m) acc2[m][n] = MFMA16(a[m], b, acc2[m][n]);
    }
  }
#pragma unroll
  for (int n = 0; n < 2; ++n) {
    int col = nb + n * 16 + ln;
    float bb = b2[col];
#pragma unroll
    for (int m = 0; m < 4; ++m)
#pragma unroll
      for (int r = 0; r < 4; ++r) {
        int row = m * 16 + q * 4 + r;
        int node = nbase + row;
        if (node < NN) n2[(size_t)node * 128 + col] = (f16)(acc2[m][n][r] + bb);
      }
  }
}

// ---------------- fused edge kernel (one layer) ----------------
// Local-optimum structure + waves_per_eu(4,4): occupancy is LDS-capped at
// 4 blocks/CU (36,352 B x4 = 145 KB), so pinning waves/EU=4 frees the
// register allocator to keep all 12 prefetch destinations (48 VGPR) live
// instead of sub-batching the gathers to fit the 64-VGPR tier.
// Probed-and-regressed neighbors: cross-phase reg state (r8: spills),
// 8 blocks/CU (r9: VGPR-32 spills), paired Dtab (r11: L2 capacity),
// 96-edge tile (r13: LDS granularity -> 2 blocks/CU), barrier-free (r4).

__global__ __launch_bounds__(256)
__attribute__((amdgpu_waves_per_eu(4, 4))) void k_edge(
    const int4* __restrict__ epack, const int* __restrict__ edst,
    const f16* __restrict__ T2, const f16* __restrict__ Dtab,
    const f16* __restrict__ We2b, const float* __restrict__ be2,
    const f16* __restrict__ Wcb, const float* __restrict__ bc,
    const f16* __restrict__ n2, float* __restrict__ h) {
  __shared__ __align__(16) f16 sC[2][64 * 136];  // U K-chunks; sC[0]->n2, sC[1]->P
  __shared__ int sSrc[64], sDst[64], sT2o[64], sIdx[64];
  __shared__ float sFrac[64];

  const int tid = threadIdx.x;
  const int e0 = blockIdx.x * 64;
  if (tid < 64) {
    int4 p = epack[e0 + tid];
    sSrc[tid] = p.x;
    sT2o[tid] = p.y;
    sIdx[tid] = p.z;
    sFrac[tid] = __int_as_float(p.w);
    sDst[tid] = edst[e0 + tid];
  }
  lds_barrier();

  const int lane = tid & 63, wave = tid >> 6;
  const int q = lane >> 4, ln = lane & 15;
  const int nb = wave * 32;

  f32x4 acc[4][2];
#pragma unroll
  for (int m = 0; m < 4; ++m)
#pragma unroll
    for (int n = 0; n < 2; ++n) acc[m][n] = 0.f;

  auto lerp_relu = [](f16x8 lo, f16x8 hi, f16x8 t2, f16 fr) -> f16x8 {
    f16x8 v = t2 + lo + (hi - lo) * fr;
    f16x8 z = {};
    return __builtin_elementwise_max(v, z);
  };
  auto pf128 = [&](int k0, f16x8* plo, f16x8* phi, f16x8* pt2, f16* pfr) {
    const int cg = tid & 15, eb = tid >> 4;
    const int col = k0 + cg * 8;
#pragma unroll
    for (int i = 0; i < 4; ++i) {
      int e = eb + i * 16;
      int off = sIdx[e] + col;
      plo[i] = *(const f16x8*)&Dtab[off];
      phi[i] = *(const f16x8*)&Dtab[off + 448];
      pt2[i] = *(const f16x8*)&T2[sT2o[e] + col];
      pfr[i] = (f16)sFrac[e];
    }
  };
  auto st128 = [&](f16* buf, const f16x8* plo, const f16x8* phi,
                   const f16x8* pt2, const f16* pfr) {
    const int cg = tid & 15, eb = tid >> 4;
#pragma unroll
    for (int i = 0; i < 4; ++i) {
      int e = eb + i * 16;
      *(f16x8*)&buf[e * 136 + cg * 8] = lerp_relu(plo[i], phi[i], pt2[i], pfr[i]);
    }
  };
  auto pf64 = [&](f16x8* plo, f16x8* phi, f16x8* pt2, f16* pfr) {
    const int cg = tid & 7, eb = tid >> 3;
    const int col = 384 + cg * 8;
#pragma unroll
    for (int i = 0; i < 2; ++i) {
      int e = eb + i * 32;
      int off = sIdx[e] + col;
      plo[i] = *(const f16x8*)&Dtab[off];
      phi[i] = *(const f16x8*)&Dtab[off + 448];
      pt2[i] = *(const f16x8*)&T2[sT2o[e] + col];
      pfr[i] = (f16)sFrac[e];
    }
  };
  auto st64 = [&](f16* buf, const f16x8* plo, const f16x8* phi,
                  const f16x8* pt2, const f16* pfr) {
    const int cg = tid & 7, eb = tid >> 3;
#pragma unroll
    for (int i = 0; i < 2; ++i) {
      int e = eb + i * 32;
      *(f16x8*)&buf[e * 136 + cg * 8] = lerp_relu(plo[i], phi[i], pt2[i], pfr[i]);
    }
  };
  auto mfma_chunk = [&](const f16* buf, int k0, int nk) {
    for (int kk = 0; kk < nk; ++kk) {
      f16x8 a[4];
#pragma unroll
      for (int m = 0; m < 4; ++m)
        a[m] = *(const f16x8*)&buf[(m * 16 + ln) * 136 + kk * 32 + q * 8];
#pragma unroll
      for (int n = 0; n < 2; ++n) {
        f16x8 b = *(const f16x8*)&We2b[(nb + n * 16 + ln) * 448 + k0 + kk * 32 + q * 8];
#pragma unroll
        for (int m = 0; m < 4; ++m) acc[m][n] = MFMA16(a[m], b, acc[m][n]);
      }
    }
  };

  // pipelined chunk schedule
  {
    f16x8 plo[4], phi[4], pt2[4]; f16 pfr[4];
    pf128(0, plo, phi, pt2, pfr);
    st128(sC[0], plo, phi, pt2, pfr);
  }
  lds_barrier();
  {
    f16x8 plo[4], phi[4], pt2[4]; f16 pfr[4];
    pf128(128, plo, phi, pt2, pfr);
    mfma_chunk(sC[0], 0, 4);
    st128(sC[1], plo, phi, pt2, pfr);
  }
  lds_barrier();
  {
    f16x8 plo[4], phi[4], pt2[4]; f16 pfr[4];
    pf128(256, plo, phi, pt2, pfr);
    mfma_chunk(sC[1], 128, 4);
    st128(sC[0], plo, phi, pt2, pfr);
  }
  lds_barrier();
  f16x8 nrows[4];  // n2 row staging: u = tid + 256*i -> e=u>>4, cg=u&15
  {
    f16x8 plo[2], phi[2], pt2[2]; f16 pfr[2];
    pf64(plo, phi, pt2, pfr);
#pragma unroll
    for (int i = 0; i < 4; ++i) {
      int u = tid + 256 * i;
      int e = u >> 4, cg = u & 15;
      nrows[i] = *(const f16x8*)&n2[(size_t)sSrc[e] * 128 + cg * 8];
    }
    mfma_chunk(sC[0], 256, 4);
    st64(sC[1], plo, phi, pt2, pfr);
  }
  lds_barrier();  // sC[0] now free for all waves

  f16* sN = sC[0];
#pragma unroll
  for (int i = 0; i < 4; ++i) {
    int u = tid + 256 * i;
    int e = u >> 4, cg = u & 15;
    *(f16x8*)&sN[e * 136 + cg * 8] = nrows[i];
  }
  mfma_chunk(sC[1], 384, 2);
  lds_barrier();  // all waves done with sC[1]; reuse as P

  // epilogue 2: P = (EE + be2) * n2[src] -> sP (= sC[1])
  f16* sP = sC[1];
  {
    float be2v[2] = {be2[nb + ln], be2[nb + 16 + ln]};
#pragma unroll
    for (int n = 0; n < 2; ++n) {
      int col = nb + n * 16 + ln;
#pragma unroll
      for (int m = 0; m < 4; ++m)
#pragma unroll
        for (int r = 0; r < 4; ++r) {
          int row = m * 16 + q * 4 + r;
          float ee = acc[m][n][r] + be2v[n];
          sP[row * 136 + col] = (f16)(ee * (float)sN[row * 136 + col]);
        }
    }
  }
  lds_barrier();

  // phase 3: m = tanh(P @ Wc^T + bc); h[dst] += m  (run-merged atomics)
  {
    f32x4 acc2[4][2];
#pragma unroll
    for (int m = 0; m < 4; ++m)
#pragma unroll
      for (int n = 0; n < 2; ++n) acc2[m][n] = 0.f;
#pragma unroll
    for (int k0 = 0; k0 < 128; k0 += 32) {
      f16x8 a[4];
#pragma unroll
      for (int m = 0; m < 4; ++m)
        a[m] = *(const f16x8*)&sP[(m * 16 + ln) * 136 + k0 + q * 8];
#pragma unroll
      for (int n = 0; n < 2; ++n) {
        f16x8 b = *(const f16x8*)&Wcb[(nb + n * 16 + ln) * 128 + k0 + q * 8];
#pragma unroll
        for (int m = 0; m < 4; ++m) acc2[m][n] = MFMA16(a[m], b, acc2[m][n]);
      }
    }
    float bcv[2] = {bc[nb + ln], bc[nb + 16 + ln]};
#pragma unroll
    for (int m = 0; m < 4; ++m) {
      int d[4];
#pragma unroll
      for (int r = 0; r < 4; ++r) d[r] = sDst[m * 16 + q * 4 + r];
#pragma unroll
      for (int n = 0; n < 2; ++n) {
        int col = nb + n * 16 + ln;
        float tv[4];
#pragma unroll
        for (int r = 0; r < 4; ++r) {
          // Pade [3/2] tanh: inputs ~1e-3 scale, err << f16 ulp
          float x = acc2[m][n][r] + bcv[n];
          x = fminf(2.f, fmaxf(-2.f, x));
          float x2 = x * x;
          tv[r] = x * (15.f + x2) * __builtin_amdgcn_rcpf(15.f + 6.f * x2);
        }
        float s = tv[0];
        int cur = d[0];
#pragma unroll
        for (int r = 1; r < 4; ++r) {
          if (d[r] == cur) {
            s += tv[r];
          } else {
            unsafeAtomicAdd(&h[(size_t)cur * 128 + col], s);
            cur = d[r];
            s = tv[r];
          }
        }
        unsafeAtomicAdd(&h[(size_t)cur * 128 + col], s);
      }
    }
  }
}

// ---------------- readout ----------------

__global__ __launch_bounds__(256) void k_read(const float* __restrict__ h,
                                              const float* __restrict__ Wr1,
                                              const float* __restrict__ br1,
                                              const float* __restrict__ Wr2,
                                              const float* __restrict__ br2,
                                              const int* __restrict__ gid,
                                              float* __restrict__ out) {
  __shared__ __align__(16) f16 sH[64 * 136];
  __shared__ __align__(16) f16 sW[128 * 136];
  __shared__ float sR4[4][64];
  const int tid = threadIdx.x;
  const int nbase = blockIdx.x * 64;
  for (int i = tid; i < 64 * 128; i += 256) {
    int e = i >> 7, d = i & 127;
    int node = nbase + e;
    float v = (node < NN) ? h[(size_t)node * 128 + d] : 0.f;
    sH[e * 136 + d] = (f16)v;
  }
  for (int i = tid; i < 128 * 128; i += 256) {
    int rr = i >> 7, d = i & 127;
    sW[rr * 136 + d] = (f16)Wr1[i];
  }
  lds_barrier();
  const int lane = tid & 63, wave = tid >> 6;
  const int q = lane >> 4, ln = lane & 15;
  const int nb = wave * 32;

  f32x4 acc[4][2];
#pragma unroll
  for (int m = 0; m < 4; ++m)
#pragma unroll
    for (int n = 0; n < 2; ++n) acc[m][n] = 0.f;
#pragma unroll
  for (int k0 = 0; k0 < 128; k0 += 32) {
    f16x8 a[4];
#pragma unroll
    for (int m = 0; m < 4; ++m)
      a[m] = *(const f16x8*)&sH[(m * 16 + ln) * 136 + k0 + q * 8];
#pragma unroll
    for (int n = 0; n < 2; ++n) {
      f16x8 b = *(const f16x8*)&sW[(nb + n * 16 + ln) * 136 + k0 + q * 8];
#pragma unroll
      for (int m = 0; m < 4; ++m) acc[m][n] = MFMA16(a[m], b, acc[m][n]);
    }
  }
#pragma unroll
  for (int m = 0; m < 4; ++m)
#pragma unroll
    for (int r = 0; r < 4; ++r) {
      float t = 0.f;
#pragma unroll
      for (int n = 0; n < 2; ++n) {
        int col = nb + n * 16 + ln;
        t += fmaxf(acc[m][n][r] + br1[col], 0.f) * Wr2[col];
      }
      t += __shfl_xor(t, 1);
      t += __shfl_xor(t, 2);
      t += __shfl_xor(t, 4);
      t += __shfl_xor(t, 8);
      if (ln == 0) sR4[wave][m * 16 + q * 4 + r] = t;
    }
  lds_barrier();
  if (tid < 64) {
    int node = nbase + tid;
    if (node < NN) {
      float s = sR4[0][tid] + sR4[1][tid] + sR4[2][tid] + sR4[3][tid] + br2[0];
      unsafeAtomicAdd(&out[gid[node]], s);
    }
  }
}

// ---------------- launch ----------------

extern "C" void kernel_launch(void* const* d_in, const int* in_sizes, int n_in,
                              void* d_out, int out_size, void* d_ws, size_t ws_size,
                              hipStream_t stream) {
  const int* Z = (const int*)d_in[0];
  const int* etype = (const int*)d_in[1];
  const float* dist = (const float*)d_in[2];
  const int* src = (const int*)d_in[3];
  const int* dst = (const int*)d_in[4];
  const int* gid = (const int*)d_in[5];
  const float* node_emb = (const float*)d_in[6];
  const float* edge_emb = (const float*)d_in[7];
  const float* Wn1 = (const float*)d_in[8];
  const float* bn1 = (const float*)d_in[9];
  const float* Wn2 = (const float*)d_in[10];
  const float* bn2 = (const float*)d_in[11];
  const float* We1 = (const float*)d_in[12];
  const float* be1 = (const float*)d_in[13];
  const float* We2 = (const float*)d_in[14];
  const float* be2 = (const float*)d_in[15];
  const float* Wc = (const float*)d_in[16];
  const float* bc = (const float*)d_in[17];
  const float* Wr1 = (const float*)d_in[18];
  const float* br1 = (const float*)d_in[19];
  const float* Wr2 = (const float*)d_in[20];
  const float* br2 = (const float*)d_in[21];
  float* out = (float*)d_out;

  char* ws = (char*)d_ws;
  float* h = (float*)(ws);                   // 51,200,000 B
  f16* n2 = (f16*)(ws + 51200000);           // 25,600,000 B
  f16* Rb = (f16*)(ws + 76800000);           //    860,160 B
  f16* We2b = (f16*)(ws + 77660160);         //    344,064 B
  f16* Wcb = (f16*)(ws + 78004224);          //     98,304 B
  f16* Wn1b = (f16*)(ws + 78102528);         //     98,304 B
  f16* Wn2b = (f16*)(ws + 78200832);         //     98,304 B
  f16* T2 = (f16*)(ws + 78299136);           //  1,075,200 B
  f16* Dtab = (f16*)(ws + 79374336);         //  5,507,712 B  -> 84,882,048
  int4* epack = (int4*)(ws + 84882048);      //  6,400,000 B  -> 91,282,048
  int* edst = (int*)(ws + 91282048);         //  1,600,000 B  -> 92,882,048
  u32* hist = (u32*)(ws + 92882048);         //    400,000 B  -> 93,282,048
  u32* cursor = (u32*)(ws + 93282048);       //    400,000 B  -> 93,682,048
  u32* excl = (u32*)(ws + 93682048);         //    400,000 B  -> 94,082,048
  u32* part = (u32*)(ws + 94082048);         //        512 B  -> 94,082,560

  // edge sort by dst (once, reused by all 3 layers)
  k_zero32<<<391, 256, 0, stream>>>(hist, NN);
  k_hist<<<1563, 256, 0, stream>>>(dst, hist);
  k_scan1<<<98, 1024, 0, stream>>>(hist, excl, part);
  k_scan2<<<1, 128, 0, stream>>>(part, 98);
  k_scan3<<<98, 1024, 0, stream>>>(excl, part, cursor);
  k_scatter<<<1563, 256, 0, stream>>>(etype, dist, src, dst, cursor, epack, edst);

  k_prepw<<<2928, 256, 0, stream>>>(Wn1, Wn2, Wc, We2, We1,
                                    Wn1b, Wn2b, Wcb, We2b, Rb);
  k_t2<<<84, 256, 0, stream>>>(edge_emb, We1, be1, T2);
  k_dtab<<<3 * (GRID + 1), 256, 0, stream>>>(Rb, Dtab);

  for (int l = 0; l < 3; ++l) {
    if (l == 0) {
      k_node0<<<1563, 256, 0, stream>>>(Z, node_emb, Wn1b, bn1, Wn2b, bn2,
                                        n2, h, out);
    } else {
      k_node<<<1563, 256, 0, stream>>>(h, Wn1b + l * 16384, bn1 + l * 128,
                                       Wn2b + l * 16384, bn2 + l * 128, n2);
    }
    k_edge<<<6250, 256, 0, stream>>>(epack, edst,
                                     T2 + l * 179200, Dtab + (size_t)l * (GRID + 1) * 448,
                                     We2b + l * 57344, be2 + l * 128,
                                     Wcb + l * 16384, bc + l * 128, n2, h);
  }
  k_read<<<1563, 256, 0, stream>>>(h, Wr1, br1, Wr2, br2, gid, out);
}